// Round 5
// baseline (215.963 us; speedup 1.0000x reference)
//
#include <hip/hip_runtime.h>

typedef unsigned short u16;
typedef unsigned int u32;
typedef float f32x4 __attribute__((ext_vector_type(4)));
typedef __bf16 bf16x8 __attribute__((ext_vector_type(8)));

#define N_TOK 4096
#define QKV_LD 1536
#define NH 4
#define HID 128
#define C_OUT 512

__device__ __forceinline__ float b2f(u16 u) { return __uint_as_float(((u32)u) << 16); }
__device__ __forceinline__ u16 f2b(float f) {
  u32 u = __float_as_uint(f);
  u32 r = (u + 0x7fffu + ((u >> 16) & 1u)) >> 16;
  return (u16)r;
}

// async global->LDS, 16B per lane; lptr must be wave-uniform (HW adds lane*16)
__device__ __forceinline__ void gload16(const u16* g, u16* l) {
  __builtin_amdgcn_global_load_lds(
      (const __attribute__((address_space(1))) void*)g,
      (__attribute__((address_space(3))) void*)l, 16, 0, 0);
}

// ---------------- 32x32 f32->bf16 transpose tile (shared device body) ------
__device__ __forceinline__ void tr32(const float* __restrict__ s,
                                     u16* __restrict__ d, int R, int C,
                                     int r0, int c0, u16 (*tile)[33]) {
  const int tx = threadIdx.x & 31, ty = threadIdx.x >> 5;  // 32 x 8
#pragma unroll
  for (int i = 0; i < 32; i += 8)
    tile[ty + i][tx] = f2b(s[(size_t)(r0 + ty + i) * C + c0 + tx]);
  __syncthreads();
#pragma unroll
  for (int i = 0; i < 32; i += 8)
    d[(size_t)(c0 + ty + i) * R + r0 + tx] = tile[tx][ty + i];
}

// ---------------- LN C=512 f32->bf16, wave-per-row (shared device body) ----
__device__ __forceinline__ void ln512_body(
    const float* __restrict__ x, const float* __restrict__ g,
    const float* __restrict__ b, u16* __restrict__ y, int row) {
  const int lane = threadIdx.x & 63;
  const float* xr = x + (size_t)row * 512;
  const int c = lane * 8;
  float4 a0 = *(const float4*)(xr + c);
  float4 a1 = *(const float4*)(xr + c + 4);
  float v[8] = {a0.x, a0.y, a0.z, a0.w, a1.x, a1.y, a1.z, a1.w};
  float s1 = 0.f, s2 = 0.f;
#pragma unroll
  for (int i = 0; i < 8; i++) { s1 += v[i]; s2 += v[i] * v[i]; }
#pragma unroll
  for (int o = 32; o; o >>= 1) { s1 += __shfl_xor(s1, o); s2 += __shfl_xor(s2, o); }
  float mean = s1 * (1.f / 512.f);
  float var = s2 * (1.f / 512.f) - mean * mean;
  float rs = rsqrtf(fmaxf(var, 0.f) + 1e-5f);
  float4 g0 = *(const float4*)(g + c), g1 = *(const float4*)(g + c + 4);
  float4 b0 = *(const float4*)(b + c), b1 = *(const float4*)(b + c + 4);
  float gg[8] = {g0.x, g0.y, g0.z, g0.w, g1.x, g1.y, g1.z, g1.w};
  float bb[8] = {b0.x, b0.y, b0.z, b0.w, b1.x, b1.y, b1.z, b1.w};
  u16 t[8];
#pragma unroll
  for (int i = 0; i < 8; i++) t[i] = f2b((v[i] - mean) * rs * gg[i] + bb[i]);
  *(uint4*)(y + (size_t)row * 512 + c) = *(const uint4*)t;
}

// ---------------- prep: ln1 + first-phase weight transposes, ONE launch ----
__global__ __launch_bounds__(256) void prep(
    const float* __restrict__ x, const float* __restrict__ ln1g,
    const float* __restrict__ ln1b, u16* __restrict__ xn,
    const float* __restrict__ Wq, const float* __restrict__ Wk,
    const float* __restrict__ Wv, const float* __restrict__ Wo,
    const float* __restrict__ W1,
    u16* __restrict__ Btqkv, u16* __restrict__ Wot, u16* __restrict__ W1t)
{
  __shared__ u16 tile[32][33];
  const int bid = blockIdx.x;
  if (bid < 1024) {
    ln512_body(x, ln1g, ln1b, xn, bid * 4 + (threadIdx.x >> 6));
    return;
  }
  const int idx = bid - 1024;
  const float* s; u16* d; int R, C, r0, c0;
  if (idx < 1024) {                    // W1
    s = W1; d = W1t; R = 512; C = 2048;
    r0 = (idx >> 6) * 32; c0 = (idx & 63) * 32;
  } else if (idx < 1792) {             // Wq|Wk|Wv
    int i = idx - 1024;
    int z = i >> 6, rem = i & 63;
    int which = z >> 2, b = z & 3;
    const float* base = (which == 0) ? Wq : (which == 1) ? Wk : Wv;
    s = base + (size_t)b * 512 * 128;
    d = Btqkv + (size_t)which * 4 * 512 * 128 + (size_t)b * 512 * 128;
    R = 512; C = 128;
    r0 = (rem >> 2) * 32; c0 = (rem & 3) * 32;
  } else {                             // Wo
    int i = idx - 1792;
    int b = i >> 4, rem = i & 15;
    s = Wo + (size_t)b * 128 * 128;
    d = Wot + (size_t)b * 128 * 128;
    R = 128; C = 128;
    r0 = (rem >> 2) * 32; c0 = (rem & 3) * 32;
  }
  tr32(s, d, R, C, r0, c0, tile);
}

// ---------------- 128x128-tile MFMA GEMM, 8 waves, dbuf LDS ---------------
// AMODE 0: A bf16, staged via global_load_lds (inverse-swizzled source)
// AMODE 1: A f32, reg-staged with inline LN (statsIn[row][16], C=512)
// AMODE 2: A bf16, reg-staged with inline LN+ReLU (statsIn[row][64], C=2048)
// LDS: linear [128][32] u16 per buffer; XOR-swizzle pair (rule 21):
//   stored slot for (row r, chunk q) = q ^ ((r>>1)&3); read mirrors it.
template <int AMODE>
__global__ __launch_bounds__(512, 4) void gemm128(
    const void* __restrict__ Av, int lda,
    const u16* __restrict__ Bt,
    void* __restrict__ C, int ldc, int outf32,
    const float* __restrict__ res,
    int Kslice, int Ktot, int atomic,
    const float* __restrict__ lng, const float* __restrict__ lnb,
    const float* __restrict__ statsIn, float* __restrict__ statsOut)
{
  __shared__ u16 As[2][128 * 32];
  __shared__ u16 Bs[2][128 * 32];
  const int bn = blockIdx.x, bm = blockIdx.y;
  const int m0 = bm * 128, n0 = bn * 128;
  const int kbase = blockIdx.z * Kslice;
  const int tid = threadIdx.x;
  const int lane = tid & 63, w = tid >> 6;
  const int wm = (w & 1) * 64;
  const int wn = (w >> 1) * 32;
  const int l16 = lane & 15, quad = lane >> 4;

  const int r_st = tid >> 2;                    // staged row 0..127
  const int x4 = (tid & 3) ^ ((r_st >> 1) & 3); // XOR-swizzle companion
  const int wbase = w * 512;                    // wave's linear LDS slice
  const int slot8 = (quad ^ ((l16 >> 1) & 3)) * 8;  // read-side swizzle

  const u16* PB = Bt + (size_t)(n0 + r_st) * Ktot + kbase + x4 * 8;
  const u16* PA16 = nullptr; const float* PA32 = nullptr;
  if constexpr (AMODE == 0)
    PA16 = (const u16*)Av + (size_t)(m0 + r_st) * lda + kbase + x4 * 8;
  else if constexpr (AMODE == 1)
    PA32 = (const float*)Av + (size_t)(m0 + r_st) * lda + kbase + (tid & 3) * 8;
  else
    PA16 = (const u16*)Av + (size_t)(m0 + r_st) * lda + kbase + (tid & 3) * 8;

  // inline-LN row stats (modes 1/2): reduce partial slots from previous stage
  float mean = 0.f, rs = 0.f;
  if constexpr (AMODE >= 1) {
    constexpr int NS = (AMODE == 1) ? 16 : 64;
    constexpr float RCPC = (AMODE == 1) ? (1.f / 512.f) : (1.f / 2048.f);
    const float* sp = statsIn + (size_t)(m0 + r_st) * (NS * 2);
    float s1 = 0.f, s2 = 0.f;
#pragma unroll 16
    for (int i = 0; i < NS; i++) { s1 += sp[i * 2]; s2 += sp[i * 2 + 1]; }
    mean = s1 * RCPC;
    float var = s2 * RCPC - mean * mean;
    rs = rsqrtf(fmaxf(var, 0.f) + 1e-5f);
  }

  float va[8], vg[8], vb[8];
  auto loadA = [&](int kk) {             // issue A + LN-param loads (regs)
    int c0 = kbase + kk + (tid & 3) * 8;
    if constexpr (AMODE == 1) {
      float4 a0 = *(const float4*)(PA32 + kk);
      float4 a1 = *(const float4*)(PA32 + kk + 4);
      va[0] = a0.x; va[1] = a0.y; va[2] = a0.z; va[3] = a0.w;
      va[4] = a1.x; va[5] = a1.y; va[6] = a1.z; va[7] = a1.w;
    } else {
      uint4 u = *(const uint4*)(PA16 + kk);
      u16 e[8]; *(uint4*)e = u;
#pragma unroll
      for (int i = 0; i < 8; i++) va[i] = b2f(e[i]);
    }
    float4 g0 = *(const float4*)(lng + c0), g1 = *(const float4*)(lng + c0 + 4);
    float4 b0 = *(const float4*)(lnb + c0), b1 = *(const float4*)(lnb + c0 + 4);
    vg[0] = g0.x; vg[1] = g0.y; vg[2] = g0.z; vg[3] = g0.w;
    vg[4] = g1.x; vg[5] = g1.y; vg[6] = g1.z; vg[7] = g1.w;
    vb[0] = b0.x; vb[1] = b0.y; vb[2] = b0.z; vb[3] = b0.w;
    vb[4] = b1.x; vb[5] = b1.y; vb[6] = b1.z; vb[7] = b1.w;
  };
  auto writeA = [&](int buf) {           // transform + swizzled ds_write
    u16 tmp[8];
#pragma unroll
    for (int i = 0; i < 8; i++) {
      float v = (va[i] - mean) * rs * vg[i] + vb[i];
      if constexpr (AMODE == 2) v = fmaxf(v, 0.f);
      tmp[i] = f2b(v);
    }
    *(int4*)&As[buf][r_st * 32 + x4 * 8] = *(const int4*)tmp;
  };

  f32x4 acc[4][2];
#pragma unroll
  for (int i = 0; i < 4; i++)
#pragma unroll
    for (int j = 0; j < 2; j++) acc[i][j] = (f32x4){0.f, 0.f, 0.f, 0.f};

  if constexpr (AMODE == 0) {
    gload16(PA16, &As[0][wbase]);
  } else {
    loadA(0); writeA(0);
  }
  gload16(PB, &Bs[0][wbase]);
  __syncthreads();

  int buf = 0;
  for (int kk = 0; kk < Kslice; kk += 32) {
    bool nxt = kk + 32 < Kslice;
    if (nxt) {                         // issue next-tile loads early (T14)
      PB += 32;
      gload16(PB, &Bs[buf ^ 1][wbase]);
      if constexpr (AMODE == 0) {
        PA16 += 32; gload16(PA16, &As[buf ^ 1][wbase]);
      } else {
        loadA(kk + 32);
      }
    }
    bf16x8 af[4], bfr[2];
#pragma unroll
    for (int mt = 0; mt < 4; mt++)
      af[mt] = *(const bf16x8*)&As[buf][(wm + mt * 16 + l16) * 32 + slot8];
#pragma unroll
    for (int nt = 0; nt < 2; nt++)
      bfr[nt] = *(const bf16x8*)&Bs[buf][(wn + nt * 16 + l16) * 32 + slot8];
#pragma unroll
    for (int mt = 0; mt < 4; mt++)
#pragma unroll
      for (int nt = 0; nt < 2; nt++)
        acc[mt][nt] = __builtin_amdgcn_mfma_f32_16x16x32_bf16(
            af[mt], bfr[nt], acc[mt][nt], 0, 0, 0);
    if constexpr (AMODE != 0) { if (nxt) writeA(buf ^ 1); }
    __syncthreads();                   // drains vmcnt+lgkm; guards buf reuse
    buf ^= 1;
  }

#pragma unroll
  for (int mt = 0; mt < 4; mt++) {
    float t1[4] = {0.f, 0.f, 0.f, 0.f}, t2[4] = {0.f, 0.f, 0.f, 0.f};
#pragma unroll
    for (int nt = 0; nt < 2; nt++)
#pragma unroll
      for (int r = 0; r < 4; r++) {
        int gr = m0 + wm + mt * 16 + quad * 4 + r;
        int gc = n0 + wn + nt * 16 + l16;
        size_t off = (size_t)gr * ldc + gc;
        float v = acc[mt][nt][r];
        if (atomic) {
          atomicAdd((float*)C + off, v);
        } else {
          if (res) v += res[off];
          if (outf32) ((float*)C)[off] = v;
          else        ((u16*)C)[off] = f2b(v);
        }
        if constexpr (AMODE == 1) { t1[r] += v; t2[r] += v * v; }
      }
    if constexpr (AMODE == 1) {        // per-row partial stats for next LN
#pragma unroll
      for (int r = 0; r < 4; r++) {
#pragma unroll
        for (int o = 8; o; o >>= 1) {
          t1[r] += __shfl_xor(t1[r], o);
          t2[r] += __shfl_xor(t2[r], o);
        }
      }
      if (l16 == 0) {
        int slot = bn * 4 + (w >> 1);
#pragma unroll
        for (int r = 0; r < 4; r++) {
          int gr = m0 + wm + mt * 16 + quad * 4 + r;
          float* sp = statsOut + ((size_t)gr * 64 + slot) * 2;
          sp[0] = t1[r]; sp[1] = t2[r];
        }
      }
    }
  }
}

// ---------------- banded attention + fused Wo + residual + ln2 stats -------
// blockIdx.x < 256: attention for 16 queries x 1 head.
// blockIdx.x >= 256: one 32x32 W2-transpose tile (Btqkv dead by now).
#define TQ 16
#define BAND 112
#define KROW 136   // u16 row stride: 272B, 68-word => 2-way-max b128 pattern
#define PROW 120   // f32 score row stride
__global__ __launch_bounds__(256) void attn_mfma(
    const u16* __restrict__ qkv, const float* __restrict__ pos,
    const float* __restrict__ ori, const int* __restrict__ batch,
    const u16* __restrict__ wot, const float* __restrict__ xres,
    float* __restrict__ out,
    const float* __restrict__ W2, u16* __restrict__ W2t,
    float* __restrict__ stats1)
{
  __shared__ u16 kv[128 * KROW];   // K band; then V^T; then Wo_h (or tr tile)
  __shared__ u16 qp[TQ * KROW];    // Q tile; then P bf16; then O bf16
  __shared__ float ps[TQ * PROW];  // f32 scores
  __shared__ float bpx[BAND], bpy[BAND], bpz[BAND];
  __shared__ float box_[BAND], boy_[BAND], boz_[BAND];
  __shared__ int bb[BAND];

  if (blockIdx.x >= 256) {         // ---- W2 transpose tile (2048x512) ----
    int idx = (blockIdx.x - 256) + blockIdx.y * 256;   // 0..1023
    int r0 = (idx >> 4) * 32, c0 = (idx & 15) * 32;
    tr32(W2, W2t, 2048, 512, r0, c0, (u16(*)[33])kv);
    return;
  }

  const int h = blockIdx.y;
  // XCD-chunked bijective swizzle over the 256 attn blocks
  const int bxs = (blockIdx.x & 7) * 32 + (blockIdx.x >> 3);
  const int i0 = bxs * TQ;
  const int j0 = i0 - 48;
  const int tid = threadIdx.x;
  const int lane = tid & 63, w = tid >> 6;
  const int l16 = lane & 15, quad = lane >> 4;

  // ---- phase 1: stage geometry, K, Q ----
  for (int t = tid; t < BAND; t += 256) {
    int j = j0 + t;
    if (j >= 0 && j < N_TOK) {
      bpx[t] = pos[j * 3 + 0]; bpy[t] = pos[j * 3 + 1]; bpz[t] = pos[j * 3 + 2];
      box_[t] = ori[j * 3 + 0]; boy_[t] = ori[j * 3 + 1]; boz_[t] = ori[j * 3 + 2];
      bb[t] = batch[j];
    } else {
      bpx[t] = bpy[t] = bpz[t] = 0.f;
      box_[t] = boy_[t] = boz_[t] = 0.f;
      bb[t] = -12345;
    }
  }
  for (int idx = tid; idx < BAND * 16; idx += 256) {  // K: 112 x 128
    int t = idx >> 4, c8 = (idx & 15) * 8;
    int j = j0 + t;
    int4 val = {0, 0, 0, 0};
    if (j >= 0 && j < N_TOK)
      val = *(const int4*)&qkv[(size_t)j * QKV_LD + 512 + h * HID + c8];
    *(int4*)&kv[t * KROW + c8] = val;
  }
  {  // Q: 16 x 128
    int q = tid >> 4, c8 = (tid & 15) * 8;
    *(int4*)&qp[q * KROW + c8] =
        *(const int4*)&qkv[(size_t)(i0 + q) * QKV_LD + h * HID + c8];
  }
  __syncthreads();

  // ---- phase 2: scores S = Q K^T / sqrt(d) + gbias, masked -> ps ----
  {
    bf16x8 af[4];
#pragma unroll
    for (int kc = 0; kc < 4; kc++)
      af[kc] = *(const bf16x8*)&qp[l16 * KROW + kc * 32 + quad * 8];
#pragma unroll
    for (int ti = 0; ti < 2; ti++) {
      int tt = w + ti * 4;                 // key tile (7 tiles of 16)
      if (tt < 7) {
        f32x4 acc = (f32x4){0.f, 0.f, 0.f, 0.f};
#pragma unroll
        for (int kc = 0; kc < 4; kc++) {
          bf16x8 bf = *(const bf16x8*)&kv[(tt * 16 + l16) * KROW + kc * 32 + quad * 8];
          acc = __builtin_amdgcn_mfma_f32_16x16x32_bf16(af[kc], bf, acc, 0, 0, 0);
        }
        int t = tt * 16 + l16;
#pragma unroll
        for (int r = 0; r < 4; r++) {
          int q = quad * 4 + r, iq = q + 48;
          int dseq = iq - t;
          bool ok = (bb[t] == bb[iq]) && (dseq <= 48) && (dseq >= -48);
          {
#pragma clang fp contract(off)
            float dx = bpx[iq] - bpx[t], dy = bpy[iq] - bpy[t], dz = bpz[iq] - bpz[t];
            float d2 = dx * dx + dy * dy + dz * dz;
            ok = ok && (d2 <= 1.0f);
          }
          float s = -1e9f;
          if (ok) {
            float gb = box_[iq] * box_[t] + boy_[iq] * boy_[t] + boz_[iq] * boz_[t];
            s = acc[r] * 0.08838834764831845f + gb;
          }
          ps[q * PROW + t] = s;
        }
      }
    }
  }
  __syncthreads();

  // ---- phase 3: stage V^T (overwrites kv) + wave-parallel softmax ----
  for (int idx = tid; idx < BAND * 32; idx += 256) {  // V rows -> V^T cols
    int t = idx >> 5, d4 = (idx & 31) * 4;
    int j = j0 + t;
    uint2 val; val.x = 0; val.y = 0;
    if (j >= 0 && j < N_TOK)
      val = *(const uint2*)&qkv[(size_t)j * QKV_LD + 1024 + h * HID + d4];
    u16 e[4] = {(u16)val.x, (u16)(val.x >> 16), (u16)val.y, (u16)(val.y >> 16)};
#pragma unroll
    for (int jj = 0; jj < 4; jj++) {     // staggered write order
      int dd = (jj + tid) & 3;
      kv[(d4 + dd) * KROW + t] = e[dd];
    }
  }
  for (int idx = tid; idx < 128 * 16; idx += 256) {  // zero pad t in [112,128)
    int d = idx >> 4, t = BAND + (idx & 15);
    kv[d * KROW + t] = 0;
  }
  {  // softmax: 16 lanes per row, 7 elems per lane, shfl_xor reduce
    int row = tid >> 4, sub = tid & 15;
    float vals[7];
    float m = -1e30f;
#pragma unroll
    for (int i = 0; i < 7; i++) {
      vals[i] = ps[row * PROW + sub + i * 16];
      m = fmaxf(m, vals[i]);
    }
#pragma unroll
    for (int o = 8; o; o >>= 1) m = fmaxf(m, __shfl_xor(m, o));
    float s = 0.f;
#pragma unroll
    for (int i = 0; i < 7; i++) { vals[i] = __expf(vals[i] - m); s += vals[i]; }
#pragma unroll
    for (int o = 8; o; o >>= 1) s += __shfl_xor(s, o);
    float inv = 1.f / s;
#pragma unroll
    for (int i = 0; i < 7; i++)
      qp[row * KROW + sub + i * 16] = f2b(vals[i] * inv);
    qp[row * KROW + BAND + sub] = 0;
  }
  __syncthreads();

  // ---- phase 5: O = P V via MFMA -> O bf16 regs ----
  u16 obuf[2][4];
  {
    bf16x8 paf[4];
#pragma unroll
    for (int kc = 0; kc < 4; kc++)
      paf[kc] = *(const bf16x8*)&qp[l16 * KROW + kc * 32 + quad * 8];
#pragma unroll
    for (int ti = 0; ti < 2; ti++) {
      int dt = w + ti * 4;
      f32x4 acc = (f32x4){0.f, 0.f, 0.f, 0.f};
#pragma unroll
      for (int kc = 0; kc < 4; kc++) {
        bf16x8 bf = *(const bf16x8*)&kv[(dt * 16 + l16) * KROW + kc * 32 + quad * 8];
        acc = __builtin_amdgcn_mfma_f32_16x16x32_bf16(paf[kc], bf, acc, 0, 0, 0);
      }
#pragma unroll
      for (int r = 0; r < 4; r++) obuf[ti][r] = f2b(acc[r]);
    }
  }
  __syncthreads();

  // ---- phase 6: O -> qp [q][d]; stage Wo_h^T into kv [e][d] ----
#pragma unroll
  for (int ti = 0; ti < 2; ti++) {
    int dt = w + ti * 4;
#pragma unroll
    for (int r = 0; r < 4; r++)
      qp[(quad * 4 + r) * KROW + dt * 16 + l16] = obuf[ti][r];
  }
  {
    const u16* wsrc = wot + (size_t)h * HID * HID;
    for (int idx = tid; idx < 128 * 16; idx += 256) {
      int e = idx >> 4, c8 = (idx & 15) * 8;
      *(int4*)&kv[e * KROW + c8] = *(const int4*)&wsrc[e * HID + c8];
    }
  }
  __syncthreads();

  // ---- phase 7: out = O @ Wo_h + x (f32) + per-row LN2 partial stats ----
  {
    bf16x8 oaf[4];
#pragma unroll
    for (int kc = 0; kc < 4; kc++)
      oaf[kc] = *(const bf16x8*)&qp[l16 * KROW + kc * 32 + quad * 8];
    float s1a[4] = {0.f, 0.f, 0.f, 0.f}, s2a[4] = {0.f, 0.f, 0.f, 0.f};
#pragma unroll
    for (int ti = 0; ti < 2; ti++) {
      int et = w + ti * 4;
      f32x4 acc = (f32x4){0.f, 0.f, 0.f, 0.f};
#pragma unroll
      for (int kc = 0; kc < 4; kc++) {
        bf16x8 bf = *(const bf16x8*)&kv[(et * 16 + l16) * KROW + kc * 32 + quad * 8];
        acc = __builtin_amdgcn_mfma_f32_16x16x32_bf16(oaf[kc], bf, acc, 0, 0, 0);
      }
#pragma unroll
      for (int r = 0; r < 4; r++) {
        int q = quad * 4 + r;
        size_t off = (size_t)(i0 + q) * C_OUT + h * HID + et * 16 + l16;
        float v = acc[r] + xres[off];
        out[off] = v;
        s1a[r] += v; s2a[r] += v * v;
      }
    }
#pragma unroll
    for (int r = 0; r < 4; r++) {
#pragma unroll
      for (int o = 8; o; o >>= 1) {
        s1a[r] += __shfl_xor(s1a[r], o);
        s2a[r] += __shfl_xor(s2a[r], o);
      }
    }
    if (l16 == 0) {
#pragma unroll
      for (int r = 0; r < 4; r++) {
        int row = i0 + quad * 4 + r;
        float* sp = stats1 + ((size_t)row * 16 + h * 4 + w) * 2;
        sp[0] = s1a[r]; sp[1] = s2a[r];
      }
    }
  }
}

// ---------------- launcher --------------------------------------------------
// 5 dispatches. ws arena (24 MB), lifetime-aliased:
//   [0,4M)     xn (prep->QKV); then stats1 [0,512K) (attn->FFN1) and
//              stats2 [512K,2.5M) (FFN1->FFN2) -- partial-slot plain stores,
//              no zero-init needed.
//   [4,16M)    qkv (QKV->attn) -> h [4,20M) (FFN1->FFN2)
//   [16,16.2M) Wot (prep->attn; dead before FFN1 writes h over it)
//   [20,22M)   Btqkv (prep->QKV) -> W2t (attn->FFN2)
//   [22,24M)   W1t (prep->FFN1)
//   x1 lives in d_out (f32); FFN2 atomically accumulates onto it.
#define MB (1048576)
extern "C" void kernel_launch(void* const* d_in, const int* in_sizes, int n_in,
                              void* d_out, int out_size, void* d_ws, size_t ws_size,
                              hipStream_t stream) {
  const float* x    = (const float*)d_in[0];
  const float* pos  = (const float*)d_in[1];
  const float* ori  = (const float*)d_in[2];
  const int*   batch = (const int*)d_in[4];
  const float* ln1g = (const float*)d_in[5];
  const float* ln1b = (const float*)d_in[6];
  const float* ln2g = (const float*)d_in[7];
  const float* ln2b = (const float*)d_in[8];
  const float* Wq = (const float*)d_in[9];
  const float* Wk = (const float*)d_in[10];
  const float* Wv = (const float*)d_in[11];
  const float* Wo = (const float*)d_in[12];
  const float* lnmg = (const float*)d_in[13];
  const float* lnmb = (const float*)d_in[14];
  const float* W1 = (const float*)d_in[15];
  const float* W2 = (const float*)d_in[16];
  float* out = (float*)d_out;

  char* ws = (char*)d_ws;
  u16* xn       = (u16*)(ws + 0);
  float* stats1 = (float*)(ws + 0);              // 512 KB (attn -> FFN1)
  float* stats2 = (float*)(ws + 512 * 1024);     // 2 MB   (FFN1 -> FFN2)
  u16* qkv   = (u16*)(ws + 4 * MB);
  u16* h     = (u16*)(ws + 4 * MB);
  u16* Wot   = (u16*)(ws + 16 * MB);
  u16* Btqkv = (u16*)(ws + 20 * MB);
  u16* W2t   = (u16*)(ws + 20 * MB);
  u16* W1t   = (u16*)(ws + 22 * MB);

  // 1. ln1 + first-phase weight transposes
  prep<<<dim3(2880), 256, 0, stream>>>(x, ln1g, ln1b, xn,
                                       Wq, Wk, Wv, Wo, W1, Btqkv, Wot, W1t);
  // 2. qkv = xn @ [Wq|Wk|Wv]
  gemm128<0><<<dim3(12, 32, 1), 512, 0, stream>>>(
      xn, 512, Btqkv, qkv, QKV_LD, 0, nullptr, 512, 512, 0,
      nullptr, nullptr, nullptr, nullptr);
  // 3. attention + fused Wo + residual -> out (f32); W2->W2t; ln2 stats
  attn_mfma<<<dim3(512, NH), 256, 0, stream>>>(qkv, pos, ori, batch, Wot, x, out,
                                               W2, W2t, stats1);
  // 4. h = LN2(out) @ W1  (inline LN via stats1; emits lnm partial stats2)
  gemm128<1><<<dim3(16, 32, 1), 512, 0, stream>>>(
      out, 512, W1t, h, 2048, 0, nullptr, 512, 512, 0,
      ln2g, ln2b, stats1, stats2);
  // 5. out += relu(LNm(h)) @ W2  (inline LN+ReLU via stats2; split-K x2)
  gemm128<2><<<dim3(4, 32, 2), 512, 0, stream>>>(
      h, 2048, W2t, out, 512, 1, nullptr, 1024, 2048, 1,
      lnmg, lnmb, stats2, nullptr);
}

// Round 6
// 214.372 us; speedup vs baseline: 1.0074x; 1.0074x over previous
//
#include <hip/hip_runtime.h>

typedef unsigned short u16;
typedef unsigned int u32;
typedef float f32x4 __attribute__((ext_vector_type(4)));
typedef __bf16 bf16x8 __attribute__((ext_vector_type(8)));

#define N_TOK 4096
#define QKV_LD 1536
#define NH 4
#define HID 128
#define C_OUT 512

__device__ __forceinline__ float b2f(u16 u) { return __uint_as_float(((u32)u) << 16); }
__device__ __forceinline__ u16 f2b(float f) {
  u32 u = __float_as_uint(f);
  u32 r = (u + 0x7fffu + ((u >> 16) & 1u)) >> 16;
  return (u16)r;
}

// async global->LDS, 16B per lane; lptr must be wave-uniform (HW adds lane*16)
__device__ __forceinline__ void gload16(const u16* g, u16* l) {
  __builtin_amdgcn_global_load_lds(
      (const __attribute__((address_space(1))) void*)g,
      (__attribute__((address_space(3))) void*)l, 16, 0, 0);
}

// ---------------- 32x32 f32->bf16 transpose tile (shared device body) ------
__device__ __forceinline__ void tr32(const float* __restrict__ s,
                                     u16* __restrict__ d, int R, int C,
                                     int r0, int c0, u16 (*tile)[33]) {
  const int tx = threadIdx.x & 31, ty = threadIdx.x >> 5;  // 32 x 8
#pragma unroll
  for (int i = 0; i < 32; i += 8)
    tile[ty + i][tx] = f2b(s[(size_t)(r0 + ty + i) * C + c0 + tx]);
  __syncthreads();
#pragma unroll
  for (int i = 0; i < 32; i += 8)
    d[(size_t)(c0 + ty + i) * R + r0 + tx] = tile[tx][ty + i];
}

// ---------------- LN C=512 f32->bf16, wave-per-row (shared device body) ----
__device__ __forceinline__ void ln512_body(
    const float* __restrict__ x, const float* __restrict__ g,
    const float* __restrict__ b, u16* __restrict__ y, int row) {
  const int lane = threadIdx.x & 63;
  const float* xr = x + (size_t)row * 512;
  const int c = lane * 8;
  float4 a0 = *(const float4*)(xr + c);
  float4 a1 = *(const float4*)(xr + c + 4);
  float v[8] = {a0.x, a0.y, a0.z, a0.w, a1.x, a1.y, a1.z, a1.w};
  float s1 = 0.f, s2 = 0.f;
#pragma unroll
  for (int i = 0; i < 8; i++) { s1 += v[i]; s2 += v[i] * v[i]; }
#pragma unroll
  for (int o = 32; o; o >>= 1) { s1 += __shfl_xor(s1, o); s2 += __shfl_xor(s2, o); }
  float mean = s1 * (1.f / 512.f);
  float var = s2 * (1.f / 512.f) - mean * mean;
  float rs = rsqrtf(fmaxf(var, 0.f) + 1e-5f);
  float4 g0 = *(const float4*)(g + c), g1 = *(const float4*)(g + c + 4);
  float4 b0 = *(const float4*)(b + c), b1 = *(const float4*)(b + c + 4);
  float gg[8] = {g0.x, g0.y, g0.z, g0.w, g1.x, g1.y, g1.z, g1.w};
  float bb[8] = {b0.x, b0.y, b0.z, b0.w, b1.x, b1.y, b1.z, b1.w};
  u16 t[8];
#pragma unroll
  for (int i = 0; i < 8; i++) t[i] = f2b((v[i] - mean) * rs * gg[i] + bb[i]);
  *(uint4*)(y + (size_t)row * 512 + c) = *(const uint4*)t;
}

// ---------------- prep: ln1 + first-phase weight transposes, ONE launch ----
__global__ __launch_bounds__(256) void prep(
    const float* __restrict__ x, const float* __restrict__ ln1g,
    const float* __restrict__ ln1b, u16* __restrict__ xn,
    const float* __restrict__ Wq, const float* __restrict__ Wk,
    const float* __restrict__ Wv, const float* __restrict__ Wo,
    const float* __restrict__ W1,
    u16* __restrict__ Btqkv, u16* __restrict__ Wot, u16* __restrict__ W1t)
{
  __shared__ u16 tile[32][33];
  const int bid = blockIdx.x;
  if (bid < 1024) {
    ln512_body(x, ln1g, ln1b, xn, bid * 4 + (threadIdx.x >> 6));
    return;
  }
  const int idx = bid - 1024;
  const float* s; u16* d; int R, C, r0, c0;
  if (idx < 1024) {                    // W1
    s = W1; d = W1t; R = 512; C = 2048;
    r0 = (idx >> 6) * 32; c0 = (idx & 63) * 32;
  } else if (idx < 1792) {             // Wq|Wk|Wv
    int i = idx - 1024;
    int z = i >> 6, rem = i & 63;
    int which = z >> 2, b = z & 3;
    const float* base = (which == 0) ? Wq : (which == 1) ? Wk : Wv;
    s = base + (size_t)b * 512 * 128;
    d = Btqkv + (size_t)which * 4 * 512 * 128 + (size_t)b * 512 * 128;
    R = 512; C = 128;
    r0 = (rem >> 2) * 32; c0 = (rem & 3) * 32;
  } else {                             // Wo
    int i = idx - 1792;
    int b = i >> 4, rem = i & 15;
    s = Wo + (size_t)b * 128 * 128;
    d = Wot + (size_t)b * 128 * 128;
    R = 128; C = 128;
    r0 = (rem >> 2) * 32; c0 = (rem & 3) * 32;
  }
  tr32(s, d, R, C, r0, c0, tile);
}

// ---------------- 128x128-tile MFMA GEMM, 8 waves, dbuf LDS ---------------
// AMODE 0: A bf16, staged via global_load_lds (inverse-swizzled source)
// AMODE 1: A f32, reg-staged with inline LN (statsIn[row][16], C=512)
// AMODE 2: A bf16, reg-staged with inline LN+ReLU (statsIn[row][64], C=2048)
// XCD panel co-location: linear id -> (bm,bn) s.t. all blocks sharing an
// A-panel (bm) have id === bm>>2 (mod 8) -> land on ONE XCD's L2.
// LDS: linear [128][32] u16 per buffer; XOR-swizzle pair (rule 21).
template <int AMODE>
__global__ __launch_bounds__(512, 4) void gemm128(
    const void* __restrict__ Av, int lda,
    const u16* __restrict__ Bt,
    void* __restrict__ C, int ldc, int outf32,
    const float* __restrict__ res,
    int Kslice, int Ktot, int atomic,
    const float* __restrict__ lng, const float* __restrict__ lnb,
    const float* __restrict__ statsIn, float* __restrict__ statsOut)
{
  __shared__ u16 As[2][128 * 32];
  __shared__ u16 Bs[2][128 * 32];
  // XCD panel co-location swizzle (bijective for any gridDim.x; z preserves
  // residue since gridDim.x*32 % 8 == 0)
  const int id = blockIdx.x + gridDim.x * blockIdx.y;
  const int xr = id & 7, xj = id >> 3;
  const int bm = xr * 4 + (xj & 3);
  const int bn = xj >> 2;
  const int m0 = bm * 128, n0 = bn * 128;
  const int kbase = blockIdx.z * Kslice;
  const int tid = threadIdx.x;
  const int lane = tid & 63, w = tid >> 6;
  const int wm = (w & 1) * 64;
  const int wn = (w >> 1) * 32;
  const int l16 = lane & 15, quad = lane >> 4;

  const int r_st = tid >> 2;                    // staged row 0..127
  const int x4 = (tid & 3) ^ ((r_st >> 1) & 3); // XOR-swizzle companion
  const int wbase = w * 512;                    // wave's linear LDS slice
  const int slot8 = (quad ^ ((l16 >> 1) & 3)) * 8;  // read-side swizzle

  const u16* PB = Bt + (size_t)(n0 + r_st) * Ktot + kbase + x4 * 8;
  const u16* PA16 = nullptr; const float* PA32 = nullptr;
  if constexpr (AMODE == 0)
    PA16 = (const u16*)Av + (size_t)(m0 + r_st) * lda + kbase + x4 * 8;
  else if constexpr (AMODE == 1)
    PA32 = (const float*)Av + (size_t)(m0 + r_st) * lda + kbase + (tid & 3) * 8;
  else
    PA16 = (const u16*)Av + (size_t)(m0 + r_st) * lda + kbase + (tid & 3) * 8;

  // inline-LN row stats (modes 1/2): vectorized partial-slot reduce
  float mean = 0.f, rs = 0.f;
  if constexpr (AMODE >= 1) {
    constexpr int NS = (AMODE == 1) ? 16 : 64;
    constexpr float RCPC = (AMODE == 1) ? (1.f / 512.f) : (1.f / 2048.f);
    const float4* sp4 = (const float4*)(statsIn + (size_t)(m0 + r_st) * (NS * 2));
    float s1 = 0.f, s2 = 0.f;
#pragma unroll
    for (int i = 0; i < NS / 2; i++) {
      float4 q = sp4[i];
      s1 += q.x + q.z; s2 += q.y + q.w;
    }
    mean = s1 * RCPC;
    float var = s2 * RCPC - mean * mean;
    rs = rsqrtf(fmaxf(var, 0.f) + 1e-5f);
  }

  float va[8], vg[8], vb[8];
  auto loadA = [&](int kk) {             // issue A + LN-param loads (regs)
    int c0 = kbase + kk + (tid & 3) * 8;
    if constexpr (AMODE == 1) {
      float4 a0 = *(const float4*)(PA32 + kk);
      float4 a1 = *(const float4*)(PA32 + kk + 4);
      va[0] = a0.x; va[1] = a0.y; va[2] = a0.z; va[3] = a0.w;
      va[4] = a1.x; va[5] = a1.y; va[6] = a1.z; va[7] = a1.w;
    } else {
      uint4 u = *(const uint4*)(PA16 + kk);
      u16 e[8]; *(uint4*)e = u;
#pragma unroll
      for (int i = 0; i < 8; i++) va[i] = b2f(e[i]);
    }
    float4 g0 = *(const float4*)(lng + c0), g1 = *(const float4*)(lng + c0 + 4);
    float4 b0 = *(const float4*)(lnb + c0), b1 = *(const float4*)(lnb + c0 + 4);
    vg[0] = g0.x; vg[1] = g0.y; vg[2] = g0.z; vg[3] = g0.w;
    vg[4] = g1.x; vg[5] = g1.y; vg[6] = g1.z; vg[7] = g1.w;
    vb[0] = b0.x; vb[1] = b0.y; vb[2] = b0.z; vb[3] = b0.w;
    vb[4] = b1.x; vb[5] = b1.y; vb[6] = b1.z; vb[7] = b1.w;
  };
  auto writeA = [&](int buf) {           // transform + swizzled ds_write
    u16 tmp[8];
#pragma unroll
    for (int i = 0; i < 8; i++) {
      float v = (va[i] - mean) * rs * vg[i] + vb[i];
      if constexpr (AMODE == 2) v = fmaxf(v, 0.f);
      tmp[i] = f2b(v);
    }
    *(int4*)&As[buf][r_st * 32 + x4 * 8] = *(const int4*)tmp;
  };

  f32x4 acc[4][2];
#pragma unroll
  for (int i = 0; i < 4; i++)
#pragma unroll
    for (int j = 0; j < 2; j++) acc[i][j] = (f32x4){0.f, 0.f, 0.f, 0.f};

  if constexpr (AMODE == 0) {
    gload16(PA16, &As[0][wbase]);
  } else {
    loadA(0); writeA(0);
  }
  gload16(PB, &Bs[0][wbase]);
  __syncthreads();

  int buf = 0;
  for (int kk = 0; kk < Kslice; kk += 32) {
    bool nxt = kk + 32 < Kslice;
    if (nxt) {                         // issue next-tile loads early (T14)
      PB += 32;
      gload16(PB, &Bs[buf ^ 1][wbase]);
      if constexpr (AMODE == 0) {
        PA16 += 32; gload16(PA16, &As[buf ^ 1][wbase]);
      } else {
        loadA(kk + 32);
      }
    }
    bf16x8 af[4], bfr[2];
#pragma unroll
    for (int mt = 0; mt < 4; mt++)
      af[mt] = *(const bf16x8*)&As[buf][(wm + mt * 16 + l16) * 32 + slot8];
#pragma unroll
    for (int nt = 0; nt < 2; nt++)
      bfr[nt] = *(const bf16x8*)&Bs[buf][(wn + nt * 16 + l16) * 32 + slot8];
#pragma unroll
    for (int mt = 0; mt < 4; mt++)
#pragma unroll
      for (int nt = 0; nt < 2; nt++)
        acc[mt][nt] = __builtin_amdgcn_mfma_f32_16x16x32_bf16(
            af[mt], bfr[nt], acc[mt][nt], 0, 0, 0);
    if constexpr (AMODE != 0) { if (nxt) writeA(buf ^ 1); }
    __syncthreads();                   // drains vmcnt+lgkm; guards buf reuse
    buf ^= 1;
  }

#pragma unroll
  for (int mt = 0; mt < 4; mt++) {
    float t1[4] = {0.f, 0.f, 0.f, 0.f}, t2[4] = {0.f, 0.f, 0.f, 0.f};
#pragma unroll
    for (int nt = 0; nt < 2; nt++)
#pragma unroll
      for (int r = 0; r < 4; r++) {
        int gr = m0 + wm + mt * 16 + quad * 4 + r;
        int gc = n0 + wn + nt * 16 + l16;
        size_t off = (size_t)gr * ldc + gc;
        float v = acc[mt][nt][r];
        if (atomic) {
          atomicAdd((float*)C + off, v);
        } else {
          if (res) v += res[off];
          if (outf32) ((float*)C)[off] = v;
          else        ((u16*)C)[off] = f2b(v);
        }
        if constexpr (AMODE == 1) { t1[r] += v; t2[r] += v * v; }
      }
    if constexpr (AMODE == 1) {        // per-row partial stats for next LN
#pragma unroll
      for (int r = 0; r < 4; r++) {
#pragma unroll
        for (int o = 8; o; o >>= 1) {
          t1[r] += __shfl_xor(t1[r], o);
          t2[r] += __shfl_xor(t2[r], o);
        }
      }
      if (l16 == 0) {
        int slot = bn * 4 + (w >> 1);
#pragma unroll
        for (int r = 0; r < 4; r++) {
          int gr = m0 + wm + mt * 16 + quad * 4 + r;
          float* sp = statsOut + ((size_t)gr * 64 + slot) * 2;
          sp[0] = t1[r]; sp[1] = t2[r];
        }
      }
    }
  }
}

// ---------------- banded attention + fused Wo + residual + ln2 stats -------
// blockIdx.x < 256: attention for 16 queries x 1 head.
// blockIdx.x >= 256: one 32x32 W2-transpose tile (Btqkv dead by now).
#define TQ 16
#define BAND 112
#define KROW 136   // u16 row stride: 272B, 68-word => 2-way-max b128 pattern
#define PROW 120   // f32 score row stride
__global__ __launch_bounds__(256) void attn_mfma(
    const u16* __restrict__ qkv, const float* __restrict__ pos,
    const float* __restrict__ ori, const int* __restrict__ batch,
    const u16* __restrict__ wot, const float* __restrict__ xres,
    float* __restrict__ out,
    const float* __restrict__ W2, u16* __restrict__ W2t,
    float* __restrict__ stats1)
{
  __shared__ u16 kv[128 * KROW];   // K band; then V^T; then Wo_h (or tr tile)
  __shared__ u16 qp[TQ * KROW];    // Q tile; then P bf16; then O bf16
  __shared__ float ps[TQ * PROW];  // f32 scores
  __shared__ float bpx[BAND], bpy[BAND], bpz[BAND];
  __shared__ float box_[BAND], boy_[BAND], boz_[BAND];
  __shared__ int bb[BAND];

  if (blockIdx.x >= 256) {         // ---- W2 transpose tile (2048x512) ----
    int idx = (blockIdx.x - 256) + blockIdx.y * 256;   // 0..1023
    int r0 = (idx >> 4) * 32, c0 = (idx & 15) * 32;
    tr32(W2, W2t, 2048, 512, r0, c0, (u16(*)[33])kv);
    return;
  }

  const int h = blockIdx.y;
  // XCD-chunked bijective swizzle over the 256 attn blocks
  const int bxs = (blockIdx.x & 7) * 32 + (blockIdx.x >> 3);
  const int i0 = bxs * TQ;
  const int j0 = i0 - 48;
  const int tid = threadIdx.x;
  const int lane = tid & 63, w = tid >> 6;
  const int l16 = lane & 15, quad = lane >> 4;

  // ---- phase 1: stage geometry, K, Q ----
  for (int t = tid; t < BAND; t += 256) {
    int j = j0 + t;
    if (j >= 0 && j < N_TOK) {
      bpx[t] = pos[j * 3 + 0]; bpy[t] = pos[j * 3 + 1]; bpz[t] = pos[j * 3 + 2];
      box_[t] = ori[j * 3 + 0]; boy_[t] = ori[j * 3 + 1]; boz_[t] = ori[j * 3 + 2];
      bb[t] = batch[j];
    } else {
      bpx[t] = bpy[t] = bpz[t] = 0.f;
      box_[t] = boy_[t] = boz_[t] = 0.f;
      bb[t] = -12345;
    }
  }
  for (int idx = tid; idx < BAND * 16; idx += 256) {  // K: 112 x 128
    int t = idx >> 4, c8 = (idx & 15) * 8;
    int j = j0 + t;
    int4 val = {0, 0, 0, 0};
    if (j >= 0 && j < N_TOK)
      val = *(const int4*)&qkv[(size_t)j * QKV_LD + 512 + h * HID + c8];
    *(int4*)&kv[t * KROW + c8] = val;
  }
  {  // Q: 16 x 128
    int q = tid >> 4, c8 = (tid & 15) * 8;
    *(int4*)&qp[q * KROW + c8] =
        *(const int4*)&qkv[(size_t)(i0 + q) * QKV_LD + h * HID + c8];
  }
  __syncthreads();

  // ---- phase 2: scores S = Q K^T / sqrt(d) + gbias, masked -> ps ----
  {
    bf16x8 af[4];
#pragma unroll
    for (int kc = 0; kc < 4; kc++)
      af[kc] = *(const bf16x8*)&qp[l16 * KROW + kc * 32 + quad * 8];
#pragma unroll
    for (int ti = 0; ti < 2; ti++) {
      int tt = w + ti * 4;                 // key tile (7 tiles of 16)
      if (tt < 7) {
        f32x4 acc = (f32x4){0.f, 0.f, 0.f, 0.f};
#pragma unroll
        for (int kc = 0; kc < 4; kc++) {
          bf16x8 bf = *(const bf16x8*)&kv[(tt * 16 + l16) * KROW + kc * 32 + quad * 8];
          acc = __builtin_amdgcn_mfma_f32_16x16x32_bf16(af[kc], bf, acc, 0, 0, 0);
        }
        int t = tt * 16 + l16;
#pragma unroll
        for (int r = 0; r < 4; r++) {
          int q = quad * 4 + r, iq = q + 48;
          int dseq = iq - t;
          bool ok = (bb[t] == bb[iq]) && (dseq <= 48) && (dseq >= -48);
          {
#pragma clang fp contract(off)
            float dx = bpx[iq] - bpx[t], dy = bpy[iq] - bpy[t], dz = bpz[iq] - bpz[t];
            float d2 = dx * dx + dy * dy + dz * dz;
            ok = ok && (d2 <= 1.0f);
          }
          float s = -1e9f;
          if (ok) {
            float gb = box_[iq] * box_[t] + boy_[iq] * boy_[t] + boz_[iq] * boz_[t];
            s = acc[r] * 0.08838834764831845f + gb;
          }
          ps[q * PROW + t] = s;
        }
      }
    }
  }
  __syncthreads();

  // ---- phase 3: stage V^T (overwrites kv) + wave-parallel softmax ----
  for (int idx = tid; idx < BAND * 32; idx += 256) {  // V rows -> V^T cols
    int t = idx >> 5, d4 = (idx & 31) * 4;
    int j = j0 + t;
    uint2 val; val.x = 0; val.y = 0;
    if (j >= 0 && j < N_TOK)
      val = *(const uint2*)&qkv[(size_t)j * QKV_LD + 1024 + h * HID + d4];
    u16 e[4] = {(u16)val.x, (u16)(val.x >> 16), (u16)val.y, (u16)(val.y >> 16)};
#pragma unroll
    for (int jj = 0; jj < 4; jj++) {     // staggered write order
      int dd = (jj + tid) & 3;
      kv[(d4 + dd) * KROW + t] = e[dd];
    }
  }
  for (int idx = tid; idx < 128 * 16; idx += 256) {  // zero pad t in [112,128)
    int d = idx >> 4, t = BAND + (idx & 15);
    kv[d * KROW + t] = 0;
  }
  {  // softmax: 16 lanes per row, 7 elems per lane, shfl_xor reduce
    int row = tid >> 4, sub = tid & 15;
    float vals[7];
    float m = -1e30f;
#pragma unroll
    for (int i = 0; i < 7; i++) {
      vals[i] = ps[row * PROW + sub + i * 16];
      m = fmaxf(m, vals[i]);
    }
#pragma unroll
    for (int o = 8; o; o >>= 1) m = fmaxf(m, __shfl_xor(m, o));
    float s = 0.f;
#pragma unroll
    for (int i = 0; i < 7; i++) { vals[i] = __expf(vals[i] - m); s += vals[i]; }
#pragma unroll
    for (int o = 8; o; o >>= 1) s += __shfl_xor(s, o);
    float inv = 1.f / s;
#pragma unroll
    for (int i = 0; i < 7; i++)
      qp[row * KROW + sub + i * 16] = f2b(vals[i] * inv);
    qp[row * KROW + BAND + sub] = 0;
  }
  __syncthreads();

  // ---- phase 5: O = P V via MFMA -> O bf16 regs ----
  u16 obuf[2][4];
  {
    bf16x8 paf[4];
#pragma unroll
    for (int kc = 0; kc < 4; kc++)
      paf[kc] = *(const bf16x8*)&qp[l16 * KROW + kc * 32 + quad * 8];
#pragma unroll
    for (int ti = 0; ti < 2; ti++) {
      int dt = w + ti * 4;
      f32x4 acc = (f32x4){0.f, 0.f, 0.f, 0.f};
#pragma unroll
      for (int kc = 0; kc < 4; kc++) {
        bf16x8 bf = *(const bf16x8*)&kv[(dt * 16 + l16) * KROW + kc * 32 + quad * 8];
        acc = __builtin_amdgcn_mfma_f32_16x16x32_bf16(paf[kc], bf, acc, 0, 0, 0);
      }
#pragma unroll
      for (int r = 0; r < 4; r++) obuf[ti][r] = f2b(acc[r]);
    }
  }
  __syncthreads();

  // ---- phase 6: O -> qp [q][d]; stage Wo_h^T into kv [e][d] ----
#pragma unroll
  for (int ti = 0; ti < 2; ti++) {
    int dt = w + ti * 4;
#pragma unroll
    for (int r = 0; r < 4; r++)
      qp[(quad * 4 + r) * KROW + dt * 16 + l16] = obuf[ti][r];
  }
  {
    const u16* wsrc = wot + (size_t)h * HID * HID;
    for (int idx = tid; idx < 128 * 16; idx += 256) {
      int e = idx >> 4, c8 = (idx & 15) * 8;
      *(int4*)&kv[e * KROW + c8] = *(const int4*)&wsrc[e * HID + c8];
    }
  }
  __syncthreads();

  // ---- phase 7: out = O @ Wo_h + x (f32) + per-row LN2 partial stats ----
  {
    bf16x8 oaf[4];
#pragma unroll
    for (int kc = 0; kc < 4; kc++)
      oaf[kc] = *(const bf16x8*)&qp[l16 * KROW + kc * 32 + quad * 8];
    float s1a[4] = {0.f, 0.f, 0.f, 0.f}, s2a[4] = {0.f, 0.f, 0.f, 0.f};
#pragma unroll
    for (int ti = 0; ti < 2; ti++) {
      int et = w + ti * 4;
      f32x4 acc = (f32x4){0.f, 0.f, 0.f, 0.f};
#pragma unroll
      for (int kc = 0; kc < 4; kc++) {
        bf16x8 bf = *(const bf16x8*)&kv[(et * 16 + l16) * KROW + kc * 32 + quad * 8];
        acc = __builtin_amdgcn_mfma_f32_16x16x32_bf16(oaf[kc], bf, acc, 0, 0, 0);
      }
#pragma unroll
      for (int r = 0; r < 4; r++) {
        int q = quad * 4 + r;
        size_t off = (size_t)(i0 + q) * C_OUT + h * HID + et * 16 + l16;
        float v = acc[r] + xres[off];
        out[off] = v;
        s1a[r] += v; s2a[r] += v * v;
      }
    }
#pragma unroll
    for (int r = 0; r < 4; r++) {
#pragma unroll
      for (int o = 8; o; o >>= 1) {
        s1a[r] += __shfl_xor(s1a[r], o);
        s2a[r] += __shfl_xor(s2a[r], o);
      }
    }
    if (l16 == 0) {
#pragma unroll
      for (int r = 0; r < 4; r++) {
        int row = i0 + quad * 4 + r;
        float* sp = stats1 + ((size_t)row * 16 + h * 4 + w) * 2;
        sp[0] = s1a[r]; sp[1] = s2a[r];
      }
    }
  }
}

// ---------------- launcher --------------------------------------------------
// 5 dispatches. ws arena (24 MB), lifetime-aliased:
//   [0,4M)     xn (prep->QKV); then stats1 [0,512K) (attn->FFN1) and
//              stats2 [512K,2.5M) (FFN1->FFN2)
//   [4,16M)    qkv (QKV->attn) -> h [4,20M) (FFN1->FFN2)
//   [16,16.2M) Wot (prep->attn; dead before FFN1 writes h over it)
//   [20,22M)   Btqkv (prep->QKV) -> W2t (attn->FFN2)
//   [22,24M)   W1t (prep->FFN1)
//   x1 lives in d_out (f32); FFN2 atomically accumulates onto it.
#define MB (1048576)
extern "C" void kernel_launch(void* const* d_in, const int* in_sizes, int n_in,
                              void* d_out, int out_size, void* d_ws, size_t ws_size,
                              hipStream_t stream) {
  const float* x    = (const float*)d_in[0];
  const float* pos  = (const float*)d_in[1];
  const float* ori  = (const float*)d_in[2];
  const int*   batch = (const int*)d_in[4];
  const float* ln1g = (const float*)d_in[5];
  const float* ln1b = (const float*)d_in[6];
  const float* ln2g = (const float*)d_in[7];
  const float* ln2b = (const float*)d_in[8];
  const float* Wq = (const float*)d_in[9];
  const float* Wk = (const float*)d_in[10];
  const float* Wv = (const float*)d_in[11];
  const float* Wo = (const float*)d_in[12];
  const float* lnmg = (const float*)d_in[13];
  const float* lnmb = (const float*)d_in[14];
  const float* W1 = (const float*)d_in[15];
  const float* W2 = (const float*)d_in[16];
  float* out = (float*)d_out;

  char* ws = (char*)d_ws;
  u16* xn       = (u16*)(ws + 0);
  float* stats1 = (float*)(ws + 0);              // 512 KB (attn -> FFN1)
  float* stats2 = (float*)(ws + 512 * 1024);     // 2 MB   (FFN1 -> FFN2)
  u16* qkv   = (u16*)(ws + 4 * MB);
  u16* h     = (u16*)(ws + 4 * MB);
  u16* Wot   = (u16*)(ws + 16 * MB);
  u16* Btqkv = (u16*)(ws + 20 * MB);
  u16* W2t   = (u16*)(ws + 20 * MB);
  u16* W1t   = (u16*)(ws + 22 * MB);

  // 1. ln1 + first-phase weight transposes
  prep<<<dim3(2880), 256, 0, stream>>>(x, ln1g, ln1b, xn,
                                       Wq, Wk, Wv, Wo, W1, Btqkv, Wot, W1t);
  // 2. qkv = xn @ [Wq|Wk|Wv]
  gemm128<0><<<dim3(12, 32, 1), 512, 0, stream>>>(
      xn, 512, Btqkv, qkv, QKV_LD, 0, nullptr, 512, 512, 0,
      nullptr, nullptr, nullptr, nullptr);
  // 3. attention + fused Wo + residual -> out (f32); W2->W2t; ln2 stats
  attn_mfma<<<dim3(512, NH), 256, 0, stream>>>(qkv, pos, ori, batch, Wot, x, out,
                                               W2, W2t, stats1);
  // 4. h = LN2(out) @ W1  (inline LN via stats1; emits lnm partial stats2)
  gemm128<1><<<dim3(16, 32, 1), 512, 0, stream>>>(
      out, 512, W1t, h, 2048, 0, nullptr, 512, 512, 0,
      ln2g, ln2b, stats1, stats2);
  // 5. out += relu(LNm(h)) @ W2  (inline LN+ReLU via stats2; split-K x2)
  gemm128<2><<<dim3(4, 32, 2), 512, 0, stream>>>(
      h, 2048, W2t, out, 512, 1, nullptr, 1024, 2048, 1,
      lnmg, lnmb, stats2, nullptr);
}

// Round 7
// 191.621 us; speedup vs baseline: 1.1270x; 1.1187x over previous
//
#include <hip/hip_runtime.h>

typedef unsigned short u16;
typedef unsigned int u32;
typedef float f32x4 __attribute__((ext_vector_type(4)));
typedef __bf16 bf16x8 __attribute__((ext_vector_type(8)));

#define N_TOK 4096
#define QKV_LD 1536
#define NH 4
#define HID 128
#define C_OUT 512

__device__ __forceinline__ float b2f(u16 u) { return __uint_as_float(((u32)u) << 16); }
__device__ __forceinline__ u16 f2b(float f) {
  u32 u = __float_as_uint(f);
  u32 r = (u + 0x7fffu + ((u >> 16) & 1u)) >> 16;
  return (u16)r;
}

// async global->LDS, 16B per lane; LDS base wave-uniform (HW adds lane*16)
__device__ __forceinline__ void gload16(const u16* g, u16* l) {
  __builtin_amdgcn_global_load_lds(
      (const __attribute__((address_space(1))) void*)g,
      (__attribute__((address_space(3))) void*)l, 16, 0, 0);
}

// ---------------- 32x32 f32->bf16 transpose tile (shared device body) ------
__device__ __forceinline__ void tr32(const float* __restrict__ s,
                                     u16* __restrict__ d, int R, int C,
                                     int r0, int c0, u16 (*tile)[33]) {
  const int tx = threadIdx.x & 31, ty = threadIdx.x >> 5;  // 32 x 8
#pragma unroll
  for (int i = 0; i < 32; i += 8)
    tile[ty + i][tx] = f2b(s[(size_t)(r0 + ty + i) * C + c0 + tx]);
  __syncthreads();
#pragma unroll
  for (int i = 0; i < 32; i += 8)
    d[(size_t)(c0 + ty + i) * R + r0 + tx] = tile[tx][ty + i];
}

// ---------------- LN C=512 f32->bf16, wave-per-row (shared device body) ----
__device__ __forceinline__ void ln512_body(
    const float* __restrict__ x, const float* __restrict__ g,
    const float* __restrict__ b, u16* __restrict__ y, int row) {
  const int lane = threadIdx.x & 63;
  const float* xr = x + (size_t)row * 512;
  const int c = lane * 8;
  float4 a0 = *(const float4*)(xr + c);
  float4 a1 = *(const float4*)(xr + c + 4);
  float v[8] = {a0.x, a0.y, a0.z, a0.w, a1.x, a1.y, a1.z, a1.w};
  float s1 = 0.f, s2 = 0.f;
#pragma unroll
  for (int i = 0; i < 8; i++) { s1 += v[i]; s2 += v[i] * v[i]; }
#pragma unroll
  for (int o = 32; o; o >>= 1) { s1 += __shfl_xor(s1, o); s2 += __shfl_xor(s2, o); }
  float mean = s1 * (1.f / 512.f);
  float var = s2 * (1.f / 512.f) - mean * mean;
  float rs = rsqrtf(fmaxf(var, 0.f) + 1e-5f);
  float4 g0 = *(const float4*)(g + c), g1 = *(const float4*)(g + c + 4);
  float4 b0 = *(const float4*)(b + c), b1 = *(const float4*)(b + c + 4);
  float gg[8] = {g0.x, g0.y, g0.z, g0.w, g1.x, g1.y, g1.z, g1.w};
  float bb[8] = {b0.x, b0.y, b0.z, b0.w, b1.x, b1.y, b1.z, b1.w};
  u16 t[8];
#pragma unroll
  for (int i = 0; i < 8; i++) t[i] = f2b((v[i] - mean) * rs * gg[i] + bb[i]);
  *(uint4*)(y + (size_t)row * 512 + c) = *(const uint4*)t;
}

// ---------------- prep: ln1 + first-phase weight transposes, ONE launch ----
__global__ __launch_bounds__(256) void prep(
    const float* __restrict__ x, const float* __restrict__ ln1g,
    const float* __restrict__ ln1b, u16* __restrict__ xn,
    const float* __restrict__ Wq, const float* __restrict__ Wk,
    const float* __restrict__ Wv, const float* __restrict__ Wo,
    const float* __restrict__ W1,
    u16* __restrict__ Btqkv, u16* __restrict__ Wot, u16* __restrict__ W1t)
{
  __shared__ u16 tile[32][33];
  const int bid = blockIdx.x;
  if (bid < 1024) {
    ln512_body(x, ln1g, ln1b, xn, bid * 4 + (threadIdx.x >> 6));
    return;
  }
  const int idx = bid - 1024;
  const float* s; u16* d; int R, C, r0, c0;
  if (idx < 1024) {                    // W1
    s = W1; d = W1t; R = 512; C = 2048;
    r0 = (idx >> 6) * 32; c0 = (idx & 63) * 32;
  } else if (idx < 1792) {             // Wq|Wk|Wv
    int i = idx - 1024;
    int z = i >> 6, rem = i & 63;
    int which = z >> 2, b = z & 3;
    const float* base = (which == 0) ? Wq : (which == 1) ? Wk : Wv;
    s = base + (size_t)b * 512 * 128;
    d = Btqkv + (size_t)which * 4 * 512 * 128 + (size_t)b * 512 * 128;
    R = 512; C = 128;
    r0 = (rem >> 2) * 32; c0 = (rem & 3) * 32;
  } else {                             // Wo
    int i = idx - 1792;
    int b = i >> 4, rem = i & 15;
    s = Wo + (size_t)b * 128 * 128;
    d = Wot + (size_t)b * 128 * 128;
    R = 128; C = 128;
    r0 = (rem >> 2) * 32; c0 = (rem & 3) * 32;
  }
  tr32(s, d, R, C, r0, c0, tile);
}

// ---------------- LN, C=512, f32 in (standalone for ln2) -------------------
__global__ __launch_bounds__(256) void ln512_f32(
    const float* __restrict__ x, const float* __restrict__ g,
    const float* __restrict__ b, u16* __restrict__ y)
{
  ln512_body(x, g, b, y, blockIdx.x * 4 + (threadIdx.x >> 6));
}

// ---------------- LN+ReLU, C=2048, bf16 in/out: block-per-row, 1 read ------
__global__ __launch_bounds__(256) void ln2048_bf16_relu(
    const u16* __restrict__ x, const float* __restrict__ g,
    const float* __restrict__ b, u16* __restrict__ y)
{
  const int row = blockIdx.x, tid = threadIdx.x;
  const int c = tid * 8;
  const u16* xr = x + (size_t)row * 2048;
  uint4 u = *(const uint4*)(xr + c);
  u16 e[8]; *(uint4*)e = u;
  float v[8];
#pragma unroll
  for (int i = 0; i < 8; i++) v[i] = b2f(e[i]);
  float s1 = 0.f, s2 = 0.f;
#pragma unroll
  for (int i = 0; i < 8; i++) { s1 += v[i]; s2 += v[i] * v[i]; }
#pragma unroll
  for (int o = 32; o; o >>= 1) { s1 += __shfl_xor(s1, o); s2 += __shfl_xor(s2, o); }
  __shared__ float red[2][4];
  int lane = tid & 63, w = tid >> 6;
  if (lane == 0) { red[0][w] = s1; red[1][w] = s2; }
  __syncthreads();
  s1 = red[0][0] + red[0][1] + red[0][2] + red[0][3];
  s2 = red[1][0] + red[1][1] + red[1][2] + red[1][3];
  float mean = s1 * (1.f / 2048.f);
  float var = s2 * (1.f / 2048.f) - mean * mean;
  float rs = rsqrtf(fmaxf(var, 0.f) + 1e-5f);
  float4 g0 = *(const float4*)(g + c), g1 = *(const float4*)(g + c + 4);
  float4 b0 = *(const float4*)(b + c), b1 = *(const float4*)(b + c + 4);
  float gg[8] = {g0.x, g0.y, g0.z, g0.w, g1.x, g1.y, g1.z, g1.w};
  float bb[8] = {b0.x, b0.y, b0.z, b0.w, b1.x, b1.y, b1.z, b1.w};
  u16 t[8];
#pragma unroll
  for (int i = 0; i < 8; i++)
    t[i] = f2b(fmaxf((v[i] - mean) * rs * gg[i] + bb[i], 0.f));
  *(uint4*)(y + (size_t)row * 2048 + c) = *(const uint4*)t;
}

// ---------------- 128x128-tile MFMA GEMM, 8 waves, K-step 64, gload_lds ----
// LDS linear [128][64] u16 per buffer (16 KB; 4 bufs = 64 KB, 2 blocks/CU).
// 16 MFMA/wave per barrier (2x the K32 version).
// Chunk swizzle (rule 21 pair): row r, chunk q stored at slot q^(r&7);
//   staging source chunk = (tid&7)^((tid>>3)&7) with linear LDS dest;
//   read slot = (kc*4+quad)^(row&7)  -> <=2-way banks (free).
// XCD panel co-location: id -> (bm,bn) with id === bm>>2 (mod 8) so all
//   blocks sharing an A-panel land on one XCD's L2.
__global__ __launch_bounds__(512, 4) void gemm128(
    const u16* __restrict__ A, int lda,
    const u16* __restrict__ Bt,
    void* __restrict__ C, int ldc, int outf32,
    const float* __restrict__ res,
    int Kslice, int Ktot, int atomic)
{
  __shared__ u16 As[2][128 * 64];
  __shared__ u16 Bs[2][128 * 64];
  const int id = blockIdx.x + gridDim.x * blockIdx.y;
  const int xr = id & 7, xj = id >> 3;
  const int bm = xr * 4 + (xj & 3);
  const int bn = xj >> 2;
  const int m0 = bm * 128, n0 = bn * 128;
  const int kbase = blockIdx.z * Kslice;
  const int tid = threadIdx.x;
  const int lane = tid & 63, w = tid >> 6;
  const int wm = (w & 1) * 64;
  const int wn = (w >> 1) * 32;
  const int l16 = lane & 15, quad = lane >> 4;

  // staging: 2 gload16 calls per matrix per buffer; call c covers rows c*64+(tid>>3)
  const int sr = tid >> 3;                       // 0..63
  const int sch = (tid & 7) ^ (sr & 7);          // inverse-swizzled source chunk
  const u16* PA = A + (size_t)(m0 + sr) * lda + kbase + sch * 8;
  const u16* PB = Bt + (size_t)(n0 + sr) * Ktot + kbase + sch * 8;
  const size_t askip = (size_t)64 * lda;         // +64 rows
  const size_t bskip = (size_t)64 * Ktot;

  f32x4 acc[4][2];
#pragma unroll
  for (int i = 0; i < 4; i++)
#pragma unroll
    for (int j = 0; j < 2; j++) acc[i][j] = (f32x4){0.f, 0.f, 0.f, 0.f};

  {
    gload16(PA, &As[0][w * 512]);
    gload16(PA + askip, &As[0][4096 + w * 512]);
    gload16(PB, &Bs[0][w * 512]);
    gload16(PB + bskip, &Bs[0][4096 + w * 512]);
  }
  __syncthreads();

  int buf = 0;
  for (int kk = 0; kk < Kslice; kk += 64) {
    if (kk + 64 < Kslice) {            // stage next K-tile while computing
      PA += 64; PB += 64;
      gload16(PA, &As[buf ^ 1][w * 512]);
      gload16(PA + askip, &As[buf ^ 1][4096 + w * 512]);
      gload16(PB, &Bs[buf ^ 1][w * 512]);
      gload16(PB + bskip, &Bs[buf ^ 1][4096 + w * 512]);
    }
#pragma unroll
    for (int kc = 0; kc < 2; kc++) {
      bf16x8 af[4], bfr[2];
#pragma unroll
      for (int mt = 0; mt < 4; mt++) {
        int row = wm + mt * 16 + l16;
        af[mt] = *(const bf16x8*)&As[buf][row * 64 + (((kc * 4 + quad) ^ (row & 7)) * 8)];
      }
#pragma unroll
      for (int nt = 0; nt < 2; nt++) {
        int row = wn + nt * 16 + l16;
        bfr[nt] = *(const bf16x8*)&Bs[buf][row * 64 + (((kc * 4 + quad) ^ (row & 7)) * 8)];
      }
#pragma unroll
      for (int mt = 0; mt < 4; mt++)
#pragma unroll
        for (int nt = 0; nt < 2; nt++)
          acc[mt][nt] = __builtin_amdgcn_mfma_f32_16x16x32_bf16(
              af[mt], bfr[nt], acc[mt][nt], 0, 0, 0);
    }
    __syncthreads();                   // drains vmcnt (stage) + lgkm (reads)
    buf ^= 1;
  }

#pragma unroll
  for (int mt = 0; mt < 4; mt++)
#pragma unroll
    for (int nt = 0; nt < 2; nt++)
#pragma unroll
      for (int r = 0; r < 4; r++) {
        int gr = m0 + wm + mt * 16 + quad * 4 + r;
        int gc = n0 + wn + nt * 16 + l16;
        size_t off = (size_t)gr * ldc + gc;
        float v = acc[mt][nt][r];
        if (atomic) {
          atomicAdd((float*)C + off, v);
        } else {
          if (res) v += res[off];
          if (outf32) ((float*)C)[off] = v;
          else        ((u16*)C)[off] = f2b(v);
        }
      }
}

// ---------------- banded attention + fused Wo + residual (+W2 transpose) ---
// blockIdx.x < 256: attention for 16 queries x 1 head.
// blockIdx.x >= 256: one 32x32 W2-transpose tile (Btqkv dead by now).
#define TQ 16
#define BAND 112
#define KROW 136   // u16 row stride: 272B, 68-word => 2-way-max b128 pattern
#define PROW 120   // f32 score row stride
__global__ __launch_bounds__(256) void attn_mfma(
    const u16* __restrict__ qkv, const float* __restrict__ pos,
    const float* __restrict__ ori, const int* __restrict__ batch,
    const u16* __restrict__ wot, const float* __restrict__ xres,
    float* __restrict__ out,
    const float* __restrict__ W2, u16* __restrict__ W2t)
{
  __shared__ u16 kv[128 * KROW];   // K band; then V^T; then Wo_h (or tr tile)
  __shared__ u16 qp[TQ * KROW];    // Q tile; then P bf16; then O bf16
  __shared__ float ps[TQ * PROW];  // f32 scores
  __shared__ float bpx[BAND], bpy[BAND], bpz[BAND];
  __shared__ float box_[BAND], boy_[BAND], boz_[BAND];
  __shared__ int bb[BAND];

  if (blockIdx.x >= 256) {         // ---- W2 transpose tile (2048x512) ----
    int idx = (blockIdx.x - 256) + blockIdx.y * 256;   // 0..1023
    int r0 = (idx >> 4) * 32, c0 = (idx & 15) * 32;
    tr32(W2, W2t, 2048, 512, r0, c0, (u16(*)[33])kv);
    return;
  }

  const int h = blockIdx.y;
  // XCD-chunked bijective swizzle over the 256 attn blocks
  const int bxs = (blockIdx.x & 7) * 32 + (blockIdx.x >> 3);
  const int i0 = bxs * TQ;
  const int j0 = i0 - 48;
  const int tid = threadIdx.x;
  const int lane = tid & 63, w = tid >> 6;
  const int l16 = lane & 15, quad = lane >> 4;

  // ---- phase 1: stage geometry, K, Q ----
  for (int t = tid; t < BAND; t += 256) {
    int j = j0 + t;
    if (j >= 0 && j < N_TOK) {
      bpx[t] = pos[j * 3 + 0]; bpy[t] = pos[j * 3 + 1]; bpz[t] = pos[j * 3 + 2];
      box_[t] = ori[j * 3 + 0]; boy_[t] = ori[j * 3 + 1]; boz_[t] = ori[j * 3 + 2];
      bb[t] = batch[j];
    } else {
      bpx[t] = bpy[t] = bpz[t] = 0.f;
      box_[t] = boy_[t] = boz_[t] = 0.f;
      bb[t] = -12345;
    }
  }
  for (int idx = tid; idx < BAND * 16; idx += 256) {  // K: 112 x 128
    int t = idx >> 4, c8 = (idx & 15) * 8;
    int j = j0 + t;
    int4 val = {0, 0, 0, 0};
    if (j >= 0 && j < N_TOK)
      val = *(const int4*)&qkv[(size_t)j * QKV_LD + 512 + h * HID + c8];
    *(int4*)&kv[t * KROW + c8] = val;
  }
  {  // Q: 16 x 128
    int q = tid >> 4, c8 = (tid & 15) * 8;
    *(int4*)&qp[q * KROW + c8] =
        *(const int4*)&qkv[(size_t)(i0 + q) * QKV_LD + h * HID + c8];
  }
  __syncthreads();

  // ---- phase 2: scores S = Q K^T / sqrt(d) + gbias, masked -> ps ----
  {
    bf16x8 af[4];
#pragma unroll
    for (int kc = 0; kc < 4; kc++)
      af[kc] = *(const bf16x8*)&qp[l16 * KROW + kc * 32 + quad * 8];
#pragma unroll
    for (int ti = 0; ti < 2; ti++) {
      int tt = w + ti * 4;                 // key tile (7 tiles of 16)
      if (tt < 7) {
        f32x4 acc = (f32x4){0.f, 0.f, 0.f, 0.f};
#pragma unroll
        for (int kc = 0; kc < 4; kc++) {
          bf16x8 bf = *(const bf16x8*)&kv[(tt * 16 + l16) * KROW + kc * 32 + quad * 8];
          acc = __builtin_amdgcn_mfma_f32_16x16x32_bf16(af[kc], bf, acc, 0, 0, 0);
        }
        int t = tt * 16 + l16;
#pragma unroll
        for (int r = 0; r < 4; r++) {
          int q = quad * 4 + r, iq = q + 48;
          int dseq = iq - t;
          bool ok = (bb[t] == bb[iq]) && (dseq <= 48) && (dseq >= -48);
          {
#pragma clang fp contract(off)
            float dx = bpx[iq] - bpx[t], dy = bpy[iq] - bpy[t], dz = bpz[iq] - bpz[t];
            float d2 = dx * dx + dy * dy + dz * dz;
            ok = ok && (d2 <= 1.0f);
          }
          float s = -1e9f;
          if (ok) {
            float gb = box_[iq] * box_[t] + boy_[iq] * boy_[t] + boz_[iq] * boz_[t];
            s = acc[r] * 0.08838834764831845f + gb;
          }
          ps[q * PROW + t] = s;
        }
      }
    }
  }
  __syncthreads();

  // ---- phase 3: stage V^T (overwrites kv) + wave-parallel softmax ----
  for (int idx = tid; idx < BAND * 32; idx += 256) {  // V rows -> V^T cols
    int t = idx >> 5, d4 = (idx & 31) * 4;
    int j = j0 + t;
    uint2 val; val.x = 0; val.y = 0;
    if (j >= 0 && j < N_TOK)
      val = *(const uint2*)&qkv[(size_t)j * QKV_LD + 1024 + h * HID + d4];
    u16 e[4] = {(u16)val.x, (u16)(val.x >> 16), (u16)val.y, (u16)(val.y >> 16)};
#pragma unroll
    for (int jj = 0; jj < 4; jj++) {     // staggered write order
      int dd = (jj + tid) & 3;
      kv[(d4 + dd) * KROW + t] = e[dd];
    }
  }
  for (int idx = tid; idx < 128 * 16; idx += 256) {  // zero pad t in [112,128)
    int d = idx >> 4, t = BAND + (idx & 15);
    kv[d * KROW + t] = 0;
  }
  {  // softmax: 16 lanes per row, 7 elems per lane, shfl_xor reduce
    int row = tid >> 4, sub = tid & 15;
    float vals[7];
    float m = -1e30f;
#pragma unroll
    for (int i = 0; i < 7; i++) {
      vals[i] = ps[row * PROW + sub + i * 16];
      m = fmaxf(m, vals[i]);
    }
#pragma unroll
    for (int o = 8; o; o >>= 1) m = fmaxf(m, __shfl_xor(m, o));
    float s = 0.f;
#pragma unroll
    for (int i = 0; i < 7; i++) { vals[i] = __expf(vals[i] - m); s += vals[i]; }
#pragma unroll
    for (int o = 8; o; o >>= 1) s += __shfl_xor(s, o);
    float inv = 1.f / s;
#pragma unroll
    for (int i = 0; i < 7; i++)
      qp[row * KROW + sub + i * 16] = f2b(vals[i] * inv);
    qp[row * KROW + BAND + sub] = 0;
  }
  __syncthreads();

  // ---- phase 5: O = P V via MFMA -> O bf16 regs ----
  u16 obuf[2][4];
  {
    bf16x8 paf[4];
#pragma unroll
    for (int kc = 0; kc < 4; kc++)
      paf[kc] = *(const bf16x8*)&qp[l16 * KROW + kc * 32 + quad * 8];
#pragma unroll
    for (int ti = 0; ti < 2; ti++) {
      int dt = w + ti * 4;
      f32x4 acc = (f32x4){0.f, 0.f, 0.f, 0.f};
#pragma unroll
      for (int kc = 0; kc < 4; kc++) {
        bf16x8 bf = *(const bf16x8*)&kv[(dt * 16 + l16) * KROW + kc * 32 + quad * 8];
        acc = __builtin_amdgcn_mfma_f32_16x16x32_bf16(paf[kc], bf, acc, 0, 0, 0);
      }
#pragma unroll
      for (int r = 0; r < 4; r++) obuf[ti][r] = f2b(acc[r]);
    }
  }
  __syncthreads();

  // ---- phase 6: O -> qp [q][d]; stage Wo_h^T into kv [e][d] ----
#pragma unroll
  for (int ti = 0; ti < 2; ti++) {
    int dt = w + ti * 4;
#pragma unroll
    for (int r = 0; r < 4; r++)
      qp[(quad * 4 + r) * KROW + dt * 16 + l16] = obuf[ti][r];
  }
  {
    const u16* wsrc = wot + (size_t)h * HID * HID;
    for (int idx = tid; idx < 128 * 16; idx += 256) {
      int e = idx >> 4, c8 = (idx & 15) * 8;
      *(int4*)&kv[e * KROW + c8] = *(const int4*)&wsrc[e * HID + c8];
    }
  }
  __syncthreads();

  // ---- phase 7: out = O @ Wo_h + x (f32) ----
  {
    bf16x8 oaf[4];
#pragma unroll
    for (int kc = 0; kc < 4; kc++)
      oaf[kc] = *(const bf16x8*)&qp[l16 * KROW + kc * 32 + quad * 8];
#pragma unroll
    for (int ti = 0; ti < 2; ti++) {
      int et = w + ti * 4;
      f32x4 acc = (f32x4){0.f, 0.f, 0.f, 0.f};
#pragma unroll
      for (int kc = 0; kc < 4; kc++) {
        bf16x8 bf = *(const bf16x8*)&kv[(et * 16 + l16) * KROW + kc * 32 + quad * 8];
        acc = __builtin_amdgcn_mfma_f32_16x16x32_bf16(oaf[kc], bf, acc, 0, 0, 0);
      }
#pragma unroll
      for (int r = 0; r < 4; r++) {
        int q = quad * 4 + r;
        size_t off = (size_t)(i0 + q) * C_OUT + h * HID + et * 16 + l16;
        out[off] = acc[r] + xres[off];
      }
    }
  }
}

// ---------------- launcher --------------------------------------------------
// 7 dispatches. ws arena (24 MB), lifetime-aliased:
//   [0,4M)     xn (prep->QKV) -> x1n (ln2->FFN1)
//   [4,16M)    qkv (QKV->attn) -> h [4,20M) (FFN1->FFN2)
//   [16,16.2M) Wot (prep->attn; dead before FFN1 writes h over it)
//   [20,22M)   Btqkv (prep->QKV) -> W2t (attn-launch transpose ->FFN2)
//   [22,24M)   W1t (prep->FFN1)
//   x1 lives in d_out (f32); FFN2 atomically accumulates onto it.
#define MB (1048576)
extern "C" void kernel_launch(void* const* d_in, const int* in_sizes, int n_in,
                              void* d_out, int out_size, void* d_ws, size_t ws_size,
                              hipStream_t stream) {
  const float* x    = (const float*)d_in[0];
  const float* pos  = (const float*)d_in[1];
  const float* ori  = (const float*)d_in[2];
  const int*   batch = (const int*)d_in[4];
  const float* ln1g = (const float*)d_in[5];
  const float* ln1b = (const float*)d_in[6];
  const float* ln2g = (const float*)d_in[7];
  const float* ln2b = (const float*)d_in[8];
  const float* Wq = (const float*)d_in[9];
  const float* Wk = (const float*)d_in[10];
  const float* Wv = (const float*)d_in[11];
  const float* Wo = (const float*)d_in[12];
  const float* lnmg = (const float*)d_in[13];
  const float* lnmb = (const float*)d_in[14];
  const float* W1 = (const float*)d_in[15];
  const float* W2 = (const float*)d_in[16];
  float* out = (float*)d_out;

  char* ws = (char*)d_ws;
  u16* xn    = (u16*)(ws + 0);
  u16* x1n   = (u16*)(ws + 0);
  u16* qkv   = (u16*)(ws + 4 * MB);
  u16* h     = (u16*)(ws + 4 * MB);
  u16* Wot   = (u16*)(ws + 16 * MB);
  u16* Btqkv = (u16*)(ws + 20 * MB);
  u16* W2t   = (u16*)(ws + 20 * MB);
  u16* W1t   = (u16*)(ws + 22 * MB);

  // 1. ln1 + first-phase weight transposes
  prep<<<dim3(2880), 256, 0, stream>>>(x, ln1g, ln1b, xn,
                                       Wq, Wk, Wv, Wo, W1, Btqkv, Wot, W1t);
  // 2. qkv = xn @ [Wq|Wk|Wv]
  gemm128<<<dim3(12, 32, 1), 512, 0, stream>>>(xn, 512, Btqkv, qkv, QKV_LD, 0,
                                               nullptr, 512, 512, 0);
  // 3. attention + fused Wo + residual -> out (f32); plus W2->W2t transpose
  attn_mfma<<<dim3(512, NH), 256, 0, stream>>>(qkv, pos, ori, batch, Wot, x, out,
                                               W2, W2t);
  // 4. ln2
  ln512_f32<<<dim3(1024), 256, 0, stream>>>(out, ln2g, ln2b, x1n);
  // 5. h = x1n @ W1
  gemm128<<<dim3(16, 32, 1), 512, 0, stream>>>(x1n, 512, W1t, h, 2048, 0,
                                               nullptr, 512, 512, 0);
  // 6. h = relu(LN(h))
  ln2048_bf16_relu<<<dim3(4096), 256, 0, stream>>>(h, lnmg, lnmb, h);
  // 7. out += h @ W2  (split-K x2, atomic f32; out already holds x1)
  gemm128<<<dim3(4, 32, 2), 512, 0, stream>>>(h, 2048, W2t, out, 512, 1,
                                              nullptr, 1024, 2048, 1);
}

// Round 8
// 182.233 us; speedup vs baseline: 1.1851x; 1.0515x over previous
//
#include <hip/hip_runtime.h>

typedef unsigned short u16;
typedef unsigned int u32;
typedef float f32x4 __attribute__((ext_vector_type(4)));
typedef __bf16 bf16x8 __attribute__((ext_vector_type(8)));

#define N_TOK 4096
#define QKV_LD 1536
#define NH 4
#define HID 128
#define C_OUT 512

__device__ __forceinline__ float b2f(u16 u) { return __uint_as_float(((u32)u) << 16); }
__device__ __forceinline__ u16 f2b(float f) {
  u32 u = __float_as_uint(f);
  u32 r = (u + 0x7fffu + ((u >> 16) & 1u)) >> 16;
  return (u16)r;
}

// async global->LDS, 16B per lane; LDS base wave-uniform (HW adds lane*16)
__device__ __forceinline__ void gload16(const u16* g, u16* l) {
  __builtin_amdgcn_global_load_lds(
      (const __attribute__((address_space(1))) void*)g,
      (__attribute__((address_space(3))) void*)l, 16, 0, 0);
}

// ---------------- 32x32 f32->bf16 transpose tile, 256-thread body ----------
__device__ __forceinline__ void tr32(const float* __restrict__ s,
                                     u16* __restrict__ d, int R, int C,
                                     int r0, int c0, u16 (*tile)[33]) {
  const int tx = threadIdx.x & 31, ty = threadIdx.x >> 5;  // 32 x 8
#pragma unroll
  for (int i = 0; i < 32; i += 8)
    tile[ty + i][tx] = f2b(s[(size_t)(r0 + ty + i) * C + c0 + tx]);
  __syncthreads();
#pragma unroll
  for (int i = 0; i < 32; i += 8)
    d[(size_t)(c0 + ty + i) * R + r0 + tx] = tile[tx][ty + i];
}

// ---------------- 32x32 transpose tile, 512-thread body --------------------
__device__ __forceinline__ void tr32_512(const float* __restrict__ s,
                                         u16* __restrict__ d, int R, int C,
                                         int r0, int c0, u16 (*tile)[33]) {
  const int tx = threadIdx.x & 31, ty = threadIdx.x >> 5;  // 32 x 16
#pragma unroll
  for (int i = 0; i < 32; i += 16)
    tile[ty + i][tx] = f2b(s[(size_t)(r0 + ty + i) * C + c0 + tx]);
  __syncthreads();
#pragma unroll
  for (int i = 0; i < 32; i += 16)
    d[(size_t)(c0 + ty + i) * R + r0 + tx] = tile[tx][ty + i];
}

// ---------------- LN C=512 f32->bf16, wave-per-row (shared device body) ----
__device__ __forceinline__ void ln512_body(
    const float* __restrict__ x, const float* __restrict__ g,
    const float* __restrict__ b, u16* __restrict__ y, int row) {
  const int lane = threadIdx.x & 63;
  const float* xr = x + (size_t)row * 512;
  const int c = lane * 8;
  float4 a0 = *(const float4*)(xr + c);
  float4 a1 = *(const float4*)(xr + c + 4);
  float v[8] = {a0.x, a0.y, a0.z, a0.w, a1.x, a1.y, a1.z, a1.w};
  float s1 = 0.f, s2 = 0.f;
#pragma unroll
  for (int i = 0; i < 8; i++) { s1 += v[i]; s2 += v[i] * v[i]; }
#pragma unroll
  for (int o = 32; o; o >>= 1) { s1 += __shfl_xor(s1, o); s2 += __shfl_xor(s2, o); }
  float mean = s1 * (1.f / 512.f);
  float var = s2 * (1.f / 512.f) - mean * mean;
  float rs = rsqrtf(fmaxf(var, 0.f) + 1e-5f);
  float4 g0 = *(const float4*)(g + c), g1 = *(const float4*)(g + c + 4);
  float4 b0 = *(const float4*)(b + c), b1 = *(const float4*)(b + c + 4);
  float gg[8] = {g0.x, g0.y, g0.z, g0.w, g1.x, g1.y, g1.z, g1.w};
  float bb[8] = {b0.x, b0.y, b0.z, b0.w, b1.x, b1.y, b1.z, b1.w};
  u16 t[8];
#pragma unroll
  for (int i = 0; i < 8; i++) t[i] = f2b((v[i] - mean) * rs * gg[i] + bb[i]);
  *(uint4*)(y + (size_t)row * 512 + c) = *(const uint4*)t;
}

// ---------------- prep: ln1 + first-phase weight transposes, ONE launch ----
__global__ __launch_bounds__(256) void prep(
    const float* __restrict__ x, const float* __restrict__ ln1g,
    const float* __restrict__ ln1b, u16* __restrict__ xn,
    const float* __restrict__ Wq, const float* __restrict__ Wk,
    const float* __restrict__ Wv, const float* __restrict__ Wo,
    const float* __restrict__ W1,
    u16* __restrict__ Btqkv, u16* __restrict__ Wot, u16* __restrict__ W1t)
{
  __shared__ u16 tile[32][33];
  const int bid = blockIdx.x;
  if (bid < 1024) {
    ln512_body(x, ln1g, ln1b, xn, bid * 4 + (threadIdx.x >> 6));
    return;
  }
  const int idx = bid - 1024;
  const float* s; u16* d; int R, C, r0, c0;
  if (idx < 1024) {                    // W1
    s = W1; d = W1t; R = 512; C = 2048;
    r0 = (idx >> 6) * 32; c0 = (idx & 63) * 32;
  } else if (idx < 1792) {             // Wq|Wk|Wv
    int i = idx - 1024;
    int z = i >> 6, rem = i & 63;
    int which = z >> 2, b = z & 3;
    const float* base = (which == 0) ? Wq : (which == 1) ? Wk : Wv;
    s = base + (size_t)b * 512 * 128;
    d = Btqkv + (size_t)which * 4 * 512 * 128 + (size_t)b * 512 * 128;
    R = 512; C = 128;
    r0 = (rem >> 2) * 32; c0 = (rem & 3) * 32;
  } else {                             // Wo
    int i = idx - 1792;
    int b = i >> 4, rem = i & 15;
    s = Wo + (size_t)b * 128 * 128;
    d = Wot + (size_t)b * 128 * 128;
    R = 128; C = 128;
    r0 = (rem >> 2) * 32; c0 = (rem & 3) * 32;
  }
  tr32(s, d, R, C, r0, c0, tile);
}

// ---------------- LN, C=512, f32 in (standalone for ln2) -------------------
__global__ __launch_bounds__(256) void ln512_f32(
    const float* __restrict__ x, const float* __restrict__ g,
    const float* __restrict__ b, u16* __restrict__ y)
{
  ln512_body(x, g, b, y, blockIdx.x * 4 + (threadIdx.x >> 6));
}

// ---------------- LN+ReLU, C=2048, bf16 in/out: block-per-row, 1 read ------
__global__ __launch_bounds__(256) void ln2048_bf16_relu(
    const u16* __restrict__ x, const float* __restrict__ g,
    const float* __restrict__ b, u16* __restrict__ y)
{
  const int row = blockIdx.x, tid = threadIdx.x;
  const int c = tid * 8;
  const u16* xr = x + (size_t)row * 2048;
  uint4 u = *(const uint4*)(xr + c);
  u16 e[8]; *(uint4*)e = u;
  float v[8];
#pragma unroll
  for (int i = 0; i < 8; i++) v[i] = b2f(e[i]);
  float s1 = 0.f, s2 = 0.f;
#pragma unroll
  for (int i = 0; i < 8; i++) { s1 += v[i]; s2 += v[i] * v[i]; }
#pragma unroll
  for (int o = 32; o; o >>= 1) { s1 += __shfl_xor(s1, o); s2 += __shfl_xor(s2, o); }
  __shared__ float red[2][4];
  int lane = tid & 63, w = tid >> 6;
  if (lane == 0) { red[0][w] = s1; red[1][w] = s2; }
  __syncthreads();
  s1 = red[0][0] + red[0][1] + red[0][2] + red[0][3];
  s2 = red[1][0] + red[1][1] + red[1][2] + red[1][3];
  float mean = s1 * (1.f / 2048.f);
  float var = s2 * (1.f / 2048.f) - mean * mean;
  float rs = rsqrtf(fmaxf(var, 0.f) + 1e-5f);
  float4 g0 = *(const float4*)(g + c), g1 = *(const float4*)(g + c + 4);
  float4 b0 = *(const float4*)(b + c), b1 = *(const float4*)(b + c + 4);
  float gg[8] = {g0.x, g0.y, g0.z, g0.w, g1.x, g1.y, g1.z, g1.w};
  float bb[8] = {b0.x, b0.y, b0.z, b0.w, b1.x, b1.y, b1.z, b1.w};
  u16 t[8];
#pragma unroll
  for (int i = 0; i < 8; i++)
    t[i] = f2b(fmaxf((v[i] - mean) * rs * gg[i] + bb[i], 0.f));
  *(uint4*)(y + (size_t)row * 2048 + c) = *(const uint4*)t;
}

// ---------------- 128x128-tile MFMA GEMM, 8 waves, K-step 64, gload_lds ----
// (unchanged from R7; see R7 notes for swizzle derivations)
__global__ __launch_bounds__(512, 4) void gemm128(
    const u16* __restrict__ A, int lda,
    const u16* __restrict__ Bt,
    void* __restrict__ C, int ldc, int outf32,
    const float* __restrict__ res,
    int Kslice, int Ktot, int atomic)
{
  __shared__ u16 As[2][128 * 64];
  __shared__ u16 Bs[2][128 * 64];
  const int id = blockIdx.x + gridDim.x * blockIdx.y;
  const int xr = id & 7, xj = id >> 3;
  const int bm = xr * 4 + (xj & 3);
  const int bn = xj >> 2;
  const int m0 = bm * 128, n0 = bn * 128;
  const int kbase = blockIdx.z * Kslice;
  const int tid = threadIdx.x;
  const int lane = tid & 63, w = tid >> 6;
  const int wm = (w & 1) * 64;
  const int wn = (w >> 1) * 32;
  const int l16 = lane & 15, quad = lane >> 4;

  const int sr = tid >> 3;                       // 0..63
  const int sch = (tid & 7) ^ (sr & 7);          // inverse-swizzled source chunk
  const u16* PA = A + (size_t)(m0 + sr) * lda + kbase + sch * 8;
  const u16* PB = Bt + (size_t)(n0 + sr) * Ktot + kbase + sch * 8;
  const size_t askip = (size_t)64 * lda;
  const size_t bskip = (size_t)64 * Ktot;

  f32x4 acc[4][2];
#pragma unroll
  for (int i = 0; i < 4; i++)
#pragma unroll
    for (int j = 0; j < 2; j++) acc[i][j] = (f32x4){0.f, 0.f, 0.f, 0.f};

  {
    gload16(PA, &As[0][w * 512]);
    gload16(PA + askip, &As[0][4096 + w * 512]);
    gload16(PB, &Bs[0][w * 512]);
    gload16(PB + bskip, &Bs[0][4096 + w * 512]);
  }
  __syncthreads();

  int buf = 0;
  for (int kk = 0; kk < Kslice; kk += 64) {
    if (kk + 64 < Kslice) {
      PA += 64; PB += 64;
      gload16(PA, &As[buf ^ 1][w * 512]);
      gload16(PA + askip, &As[buf ^ 1][4096 + w * 512]);
      gload16(PB, &Bs[buf ^ 1][w * 512]);
      gload16(PB + bskip, &Bs[buf ^ 1][4096 + w * 512]);
    }
#pragma unroll
    for (int kc = 0; kc < 2; kc++) {
      bf16x8 af[4], bfr[2];
#pragma unroll
      for (int mt = 0; mt < 4; mt++) {
        int row = wm + mt * 16 + l16;
        af[mt] = *(const bf16x8*)&As[buf][row * 64 + (((kc * 4 + quad) ^ (row & 7)) * 8)];
      }
#pragma unroll
      for (int nt = 0; nt < 2; nt++) {
        int row = wn + nt * 16 + l16;
        bfr[nt] = *(const bf16x8*)&Bs[buf][row * 64 + (((kc * 4 + quad) ^ (row & 7)) * 8)];
      }
#pragma unroll
      for (int mt = 0; mt < 4; mt++)
#pragma unroll
        for (int nt = 0; nt < 2; nt++)
          acc[mt][nt] = __builtin_amdgcn_mfma_f32_16x16x32_bf16(
              af[mt], bfr[nt], acc[mt][nt], 0, 0, 0);
    }
    __syncthreads();
    buf ^= 1;
  }

#pragma unroll
  for (int mt = 0; mt < 4; mt++)
#pragma unroll
    for (int nt = 0; nt < 2; nt++)
#pragma unroll
      for (int r = 0; r < 4; r++) {
        int gr = m0 + wm + mt * 16 + quad * 4 + r;
        int gc = n0 + wn + nt * 16 + l16;
        size_t off = (size_t)gr * ldc + gc;
        float v = acc[mt][nt][r];
        if (atomic) {
          atomicAdd((float*)C + off, v);
        } else {
          if (res) v += res[off];
          if (outf32) ((float*)C)[off] = v;
          else        ((u16*)C)[off] = f2b(v);
        }
      }
}

// ---------------- banded attention TQ=32, 512 thr + fused Wo (+W2 tr) ------
// blockIdx.x < 128: attention, 32 queries x 1 head; band t in [0,128),
//   j = i0-48+t (covers i0-48 .. i0+79; queries at t_q = q+48).
// blockIdx.x >= 128: one 32x32 W2-transpose tile (Btqkv dead by now).
// Per wave (8 waves): the two (tile,qt) pairs p = w + 8*ti share the same
// B-row tile (tt/dt/et = w), so B-fragments load once per phase.
#define TQ 32
#define BAND 128
#define KROW 136   // u16 row stride: 272B, 68-word => 2-way-max b128 pattern
#define PROW 132   // f32 score row stride (132%32=4 -> <=2-way banks)
__global__ __launch_bounds__(512) void attn_mfma(
    const u16* __restrict__ qkv, const float* __restrict__ pos,
    const float* __restrict__ ori, const int* __restrict__ batch,
    const u16* __restrict__ wot, const float* __restrict__ xres,
    float* __restrict__ out,
    const float* __restrict__ W2, u16* __restrict__ W2t)
{
  __shared__ u16 kv[128 * KROW];   // K band; then V^T; then Wo_h (or tr tile)
  __shared__ u16 qp[TQ * KROW];    // Q tile; then P bf16; then O bf16
  __shared__ float ps[TQ * PROW];  // f32 scores
  __shared__ float bpx[BAND], bpy[BAND], bpz[BAND];
  __shared__ float box_[BAND], boy_[BAND], boz_[BAND];
  __shared__ int bb[BAND];

  if (blockIdx.x >= 128) {         // ---- W2 transpose tile (2048x512) ----
    int idx = (blockIdx.x - 128) + blockIdx.y * 256;   // 0..1023
    int r0 = (idx >> 4) * 32, c0 = (idx & 15) * 32;
    tr32_512(W2, W2t, 2048, 512, r0, c0, (u16(*)[33])kv);
    return;
  }

  const int h = blockIdx.y;
  // XCD-chunked bijective swizzle over the 128 attn x-blocks
  const int bxs = (blockIdx.x & 7) * 16 + (blockIdx.x >> 3);
  const int i0 = bxs * TQ;
  const int j0 = i0 - 48;
  const int tid = threadIdx.x;
  const int lane = tid & 63, w = tid >> 6;          // w in 0..7
  const int l16 = lane & 15, quad = lane >> 4;

  // ---- phase 1: stage geometry, K, Q ----
  if (tid < BAND) {
    int t = tid, j = j0 + t;
    if (j >= 0 && j < N_TOK) {
      bpx[t] = pos[j * 3 + 0]; bpy[t] = pos[j * 3 + 1]; bpz[t] = pos[j * 3 + 2];
      box_[t] = ori[j * 3 + 0]; boy_[t] = ori[j * 3 + 1]; boz_[t] = ori[j * 3 + 2];
      bb[t] = batch[j];
    } else {
      bpx[t] = bpy[t] = bpz[t] = 0.f;
      box_[t] = boy_[t] = boz_[t] = 0.f;
      bb[t] = -12345;
    }
  }
  for (int idx = tid; idx < BAND * 16; idx += 512) {  // K: 128 x 128, 16B
    int t = idx >> 4, c8 = (idx & 15) * 8;
    int j = j0 + t;
    int4 val = {0, 0, 0, 0};
    if (j >= 0 && j < N_TOK)
      val = *(const int4*)&qkv[(size_t)j * QKV_LD + 512 + h * HID + c8];
    *(int4*)&kv[t * KROW + c8] = val;
  }
  {  // Q: 32 x 128, one 16B chunk per thread
    int q = tid >> 4, c8 = (tid & 15) * 8;
    *(int4*)&qp[q * KROW + c8] =
        *(const int4*)&qkv[(size_t)(i0 + q) * QKV_LD + h * HID + c8];
  }
  __syncthreads();

  // ---- phase 2: scores S = Q K^T / sqrt(d) + gbias, masked -> ps ----
  {
    bf16x8 bf[4];                       // K fragments, row tile tt = w
#pragma unroll
    for (int kc = 0; kc < 4; kc++)
      bf[kc] = *(const bf16x8*)&kv[(w * 16 + l16) * KROW + kc * 32 + quad * 8];
    const int t = w * 16 + l16;
#pragma unroll
    for (int qt = 0; qt < 2; qt++) {
      bf16x8 af[4];
#pragma unroll
      for (int kc = 0; kc < 4; kc++)
        af[kc] = *(const bf16x8*)&qp[(qt * 16 + l16) * KROW + kc * 32 + quad * 8];
      f32x4 acc = (f32x4){0.f, 0.f, 0.f, 0.f};
#pragma unroll
      for (int kc = 0; kc < 4; kc++)
        acc = __builtin_amdgcn_mfma_f32_16x16x32_bf16(af[kc], bf[kc], acc, 0, 0, 0);
#pragma unroll
      for (int r = 0; r < 4; r++) {
        int q = qt * 16 + quad * 4 + r, iq = q + 48;
        int dseq = iq - t;
        bool ok = (bb[t] == bb[iq]) && (dseq <= 48) && (dseq >= -48);
        {
#pragma clang fp contract(off)
          float dx = bpx[iq] - bpx[t], dy = bpy[iq] - bpy[t], dz = bpz[iq] - bpz[t];
          float d2 = dx * dx + dy * dy + dz * dz;
          ok = ok && (d2 <= 1.0f);
        }
        float s = -1e9f;
        if (ok) {
          float gb = box_[iq] * box_[t] + boy_[iq] * boy_[t] + boz_[iq] * boz_[t];
          s = acc[r] * 0.08838834764831845f + gb;
        }
        ps[q * PROW + t] = s;
      }
    }
  }
  __syncthreads();

  // ---- phase 3: stage V^T (overwrites kv) + wave-parallel softmax ----
  for (int idx = tid; idx < BAND * 32; idx += 512) {  // V rows -> V^T cols
    int t = idx >> 5, d4 = (idx & 31) * 4;
    int j = j0 + t;
    uint2 val; val.x = 0; val.y = 0;
    if (j >= 0 && j < N_TOK)
      val = *(const uint2*)&qkv[(size_t)j * QKV_LD + 1024 + h * HID + d4];
    u16 e[4] = {(u16)val.x, (u16)(val.x >> 16), (u16)val.y, (u16)(val.y >> 16)};
#pragma unroll
    for (int jj = 0; jj < 4; jj++) {     // staggered write order
      int dd = (jj + tid) & 3;
      kv[(d4 + dd) * KROW + t] = e[dd];
    }
  }
  {  // softmax: 32 rows x 16 lanes, 8 elems per lane, shfl_xor reduce
    int row = tid >> 4, sub = tid & 15;
    float vals[8];
    float m = -1e30f;
#pragma unroll
    for (int i = 0; i < 8; i++) {
      vals[i] = ps[row * PROW + sub + i * 16];
      m = fmaxf(m, vals[i]);
    }
#pragma unroll
    for (int o = 8; o; o >>= 1) m = fmaxf(m, __shfl_xor(m, o));
    float s = 0.f;
#pragma unroll
    for (int i = 0; i < 8; i++) { vals[i] = __expf(vals[i] - m); s += vals[i]; }
#pragma unroll
    for (int o = 8; o; o >>= 1) s += __shfl_xor(s, o);
    float inv = 1.f / s;
#pragma unroll
    for (int i = 0; i < 8; i++)
      qp[row * KROW + sub + i * 16] = f2b(vals[i] * inv);
  }
  __syncthreads();

  // ---- phase 5: O = P V via MFMA (A=P[q][t], B=V^T[d][t]) -> O bf16 regs --
  u16 obuf[2][4];
  {
    bf16x8 bf[4];                       // V^T fragments, row tile dt = w
#pragma unroll
    for (int kc = 0; kc < 4; kc++)
      bf[kc] = *(const bf16x8*)&kv[(w * 16 + l16) * KROW + kc * 32 + quad * 8];
#pragma unroll
    for (int qt = 0; qt < 2; qt++) {
      bf16x8 paf[4];
#pragma unroll
      for (int kc = 0; kc < 4; kc++)
        paf[kc] = *(const bf16x8*)&qp[(qt * 16 + l16) * KROW + kc * 32 + quad * 8];
      f32x4 acc = (f32x4){0.f, 0.f, 0.f, 0.f};
#pragma unroll
      for (int kc = 0; kc < 4; kc++)
        acc = __builtin_amdgcn_mfma_f32_16x16x32_bf16(paf[kc], bf[kc], acc, 0, 0, 0);
#pragma unroll
      for (int r = 0; r < 4; r++) obuf[qt][r] = f2b(acc[r]);
    }
  }
  __syncthreads();   // all reads of qp (P) and kv (V^T) complete

  // ---- phase 6: O -> qp [q][d]; stage Wo_h^T into kv [e][d] ----
#pragma unroll
  for (int qt = 0; qt < 2; qt++) {
#pragma unroll
    for (int r = 0; r < 4; r++)
      qp[(qt * 16 + quad * 4 + r) * KROW + w * 16 + l16] = obuf[qt][r];
  }
  {
    const u16* wsrc = wot + (size_t)h * HID * HID;
    for (int idx = tid; idx < 128 * 16; idx += 512) {
      int e = idx >> 4, c8 = (idx & 15) * 8;
      *(int4*)&kv[e * KROW + c8] = *(const int4*)&wsrc[e * HID + c8];
    }
  }
  __syncthreads();

  // ---- phase 7: out = O @ Wo_h + x (f32), A=O[q][d], B=Wo^T[e][d] ----
  {
    bf16x8 bf[4];                       // Wo fragments, row tile et = w
#pragma unroll
    for (int kc = 0; kc < 4; kc++)
      bf[kc] = *(const bf16x8*)&kv[(w * 16 + l16) * KROW + kc * 32 + quad * 8];
#pragma unroll
    for (int qt = 0; qt < 2; qt++) {
      bf16x8 oaf[4];
#pragma unroll
      for (int kc = 0; kc < 4; kc++)
        oaf[kc] = *(const bf16x8*)&qp[(qt * 16 + l16) * KROW + kc * 32 + quad * 8];
      f32x4 acc = (f32x4){0.f, 0.f, 0.f, 0.f};
#pragma unroll
      for (int kc = 0; kc < 4; kc++)
        acc = __builtin_amdgcn_mfma_f32_16x16x32_bf16(oaf[kc], bf[kc], acc, 0, 0, 0);
#pragma unroll
      for (int r = 0; r < 4; r++) {
        int q = qt * 16 + quad * 4 + r;
        size_t off = (size_t)(i0 + q) * C_OUT + h * HID + w * 16 + l16;
        out[off] = acc[r] + xres[off];
      }
    }
  }
}

// ---------------- launcher --------------------------------------------------
// 7 dispatches. ws arena (24 MB), lifetime-aliased:
//   [0,4M)     xn (prep->QKV) -> x1n (ln2->FFN1)
//   [4,16M)    qkv (QKV->attn) -> h [4,20M) (FFN1->FFN2)
//   [16,16.2M) Wot (prep->attn; dead before FFN1 writes h over it)
//   [20,22M)   Btqkv (prep->QKV) -> W2t (attn-launch transpose ->FFN2)
//   [22,24M)   W1t (prep->FFN1)
//   x1 lives in d_out (f32); FFN2 atomically accumulates onto it.
#define MB (1048576)
extern "C" void kernel_launch(void* const* d_in, const int* in_sizes, int n_in,
                              void* d_out, int out_size, void* d_ws, size_t ws_size,
                              hipStream_t stream) {
  const float* x    = (const float*)d_in[0];
  const float* pos  = (const float*)d_in[1];
  const float* ori  = (const float*)d_in[2];
  const int*   batch = (const int*)d_in[4];
  const float* ln1g = (const float*)d_in[5];
  const float* ln1b = (const float*)d_in[6];
  const float* ln2g = (const float*)d_in[7];
  const float* ln2b = (const float*)d_in[8];
  const float* Wq = (const float*)d_in[9];
  const float* Wk = (const float*)d_in[10];
  const float* Wv = (const float*)d_in[11];
  const float* Wo = (const float*)d_in[12];
  const float* lnmg = (const float*)d_in[13];
  const float* lnmb = (const float*)d_in[14];
  const float* W1 = (const float*)d_in[15];
  const float* W2 = (const float*)d_in[16];
  float* out = (float*)d_out;

  char* ws = (char*)d_ws;
  u16* xn    = (u16*)(ws + 0);
  u16* x1n   = (u16*)(ws + 0);
  u16* qkv   = (u16*)(ws + 4 * MB);
  u16* h     = (u16*)(ws + 4 * MB);
  u16* Wot   = (u16*)(ws + 16 * MB);
  u16* Btqkv = (u16*)(ws + 20 * MB);
  u16* W2t   = (u16*)(ws + 20 * MB);
  u16* W1t   = (u16*)(ws + 22 * MB);

  // 1. ln1 + first-phase weight transposes
  prep<<<dim3(2880), 256, 0, stream>>>(x, ln1g, ln1b, xn,
                                       Wq, Wk, Wv, Wo, W1, Btqkv, Wot, W1t);
  // 2. qkv = xn @ [Wq|Wk|Wv]
  gemm128<<<dim3(12, 32, 1), 512, 0, stream>>>(xn, 512, Btqkv, qkv, QKV_LD, 0,
                                               nullptr, 512, 512, 0);
  // 3. attention (TQ=32) + fused Wo + residual -> out (f32); plus W2->W2t
  attn_mfma<<<dim3(384, NH), 512, 0, stream>>>(qkv, pos, ori, batch, Wot, x, out,
                                               W2, W2t);
  // 4. ln2
  ln512_f32<<<dim3(1024), 256, 0, stream>>>(out, ln2g, ln2b, x1n);
  // 5. h = x1n @ W1
  gemm128<<<dim3(16, 32, 1), 512, 0, stream>>>(x1n, 512, W1t, h, 2048, 0,
                                               nullptr, 512, 512, 0);
  // 6. h = relu(LN(h))
  ln2048_bf16_relu<<<dim3(4096), 256, 0, stream>>>(h, lnmg, lnmb, h);
  // 7. out += h @ W2  (split-K x2, atomic f32; out already holds x1)
  gemm128<<<dim3(4, 32, 2), 512, 0, stream>>>(h, 2048, W2t, out, 512, 1,
                                              nullptr, 1024, 2048, 1);
}

// Round 10
// 179.269 us; speedup vs baseline: 1.2047x; 1.0165x over previous
//
#include <hip/hip_runtime.h>

typedef unsigned short u16;
typedef unsigned int u32;
typedef float f32x4 __attribute__((ext_vector_type(4)));
typedef __bf16 bf16x8 __attribute__((ext_vector_type(8)));

#define N_TOK 4096
#define QKV_LD 1536
#define NH 4
#define HID 128
#define C_OUT 512

__device__ __forceinline__ float b2f(u16 u) { return __uint_as_float(((u32)u) << 16); }
__device__ __forceinline__ u16 f2b(float f) {
  u32 u = __float_as_uint(f);
  u32 r = (u + 0x7fffu + ((u >> 16) & 1u)) >> 16;
  return (u16)r;
}

// async global->LDS, 16B per lane; LDS base wave-uniform (HW adds lane*16)
__device__ __forceinline__ void gload16(const u16* g, u16* l) {
  __builtin_amdgcn_global_load_lds(
      (const __attribute__((address_space(1))) void*)g,
      (__attribute__((address_space(3))) void*)l, 16, 0, 0);
}

// ---------------- 32x32 f32->bf16 transpose tile, 256-thread body ----------
__device__ __forceinline__ void tr32(const float* __restrict__ s,
                                     u16* __restrict__ d, int R, int C,
                                     int r0, int c0, u16 (*tile)[33]) {
  const int tx = threadIdx.x & 31, ty = threadIdx.x >> 5;  // 32 x 8
#pragma unroll
  for (int i = 0; i < 32; i += 8)
    tile[ty + i][tx] = f2b(s[(size_t)(r0 + ty + i) * C + c0 + tx]);
  __syncthreads();
#pragma unroll
  for (int i = 0; i < 32; i += 8)
    d[(size_t)(c0 + ty + i) * R + r0 + tx] = tile[tx][ty + i];
}

// ---------------- 32x32 transpose tile, 512-thread body --------------------
__device__ __forceinline__ void tr32_512(const float* __restrict__ s,
                                         u16* __restrict__ d, int R, int C,
                                         int r0, int c0, u16 (*tile)[33]) {
  const int tx = threadIdx.x & 31, ty = threadIdx.x >> 5;  // 32 x 16
#pragma unroll
  for (int i = 0; i < 32; i += 16)
    tile[ty + i][tx] = f2b(s[(size_t)(r0 + ty + i) * C + c0 + tx]);
  __syncthreads();
#pragma unroll
  for (int i = 0; i < 32; i += 16)
    d[(size_t)(c0 + ty + i) * R + r0 + tx] = tile[tx][ty + i];
}

// ---------------- LN C=512 f32->bf16, wave-per-row (shared device body) ----
__device__ __forceinline__ void ln512_body(
    const float* __restrict__ x, const float* __restrict__ g,
    const float* __restrict__ b, u16* __restrict__ y, int row) {
  const int lane = threadIdx.x & 63;
  const float* xr = x + (size_t)row * 512;
  const int c = lane * 8;
  float4 a0 = *(const float4*)(xr + c);
  float4 a1 = *(const float4*)(xr + c + 4);
  float v[8] = {a0.x, a0.y, a0.z, a0.w, a1.x, a1.y, a1.z, a1.w};
  float s1 = 0.f, s2 = 0.f;
#pragma unroll
  for (int i = 0; i < 8; i++) { s1 += v[i]; s2 += v[i] * v[i]; }
#pragma unroll
  for (int o = 32; o; o >>= 1) { s1 += __shfl_xor(s1, o); s2 += __shfl_xor(s2, o); }
  float mean = s1 * (1.f / 512.f);
  float var = s2 * (1.f / 512.f) - mean * mean;
  float rs = rsqrtf(fmaxf(var, 0.f) + 1e-5f);
  float4 g0 = *(const float4*)(g + c), g1 = *(const float4*)(g + c + 4);
  float4 b0 = *(const float4*)(b + c), b1 = *(const float4*)(b + c + 4);
  float gg[8] = {g0.x, g0.y, g0.z, g0.w, g1.x, g1.y, g1.z, g1.w};
  float bb[8] = {b0.x, b0.y, b0.z, b0.w, b1.x, b1.y, b1.z, b1.w};
  u16 t[8];
#pragma unroll
  for (int i = 0; i < 8; i++) t[i] = f2b((v[i] - mean) * rs * gg[i] + bb[i]);
  *(uint4*)(y + (size_t)row * 512 + c) = *(const uint4*)t;
}

// ---------------- prep: ln1 + first-phase weight transposes, ONE launch ----
__global__ __launch_bounds__(256) void prep(
    const float* __restrict__ x, const float* __restrict__ ln1g,
    const float* __restrict__ ln1b, u16* __restrict__ xn,
    const float* __restrict__ Wq, const float* __restrict__ Wk,
    const float* __restrict__ Wv, const float* __restrict__ Wo,
    const float* __restrict__ W1,
    u16* __restrict__ Btqkv, u16* __restrict__ Wot, u16* __restrict__ W1t)
{
  __shared__ u16 tile[32][33];
  const int bid = blockIdx.x;
  if (bid < 1024) {
    ln512_body(x, ln1g, ln1b, xn, bid * 4 + (threadIdx.x >> 6));
    return;
  }
  const int idx = bid - 1024;
  const float* s; u16* d; int R, C, r0, c0;
  if (idx < 1024) {                    // W1
    s = W1; d = W1t; R = 512; C = 2048;
    r0 = (idx >> 6) * 32; c0 = (idx & 63) * 32;
  } else if (idx < 1792) {             // Wq|Wk|Wv
    int i = idx - 1024;
    int z = i >> 6, rem = i & 63;
    int which = z >> 2, b = z & 3;
    const float* base = (which == 0) ? Wq : (which == 1) ? Wk : Wv;
    s = base + (size_t)b * 512 * 128;
    d = Btqkv + (size_t)which * 4 * 512 * 128 + (size_t)b * 512 * 128;
    R = 512; C = 128;
    r0 = (rem >> 2) * 32; c0 = (rem & 3) * 32;
  } else {                             // Wo
    int i = idx - 1792;
    int b = i >> 4, rem = i & 15;
    s = Wo + (size_t)b * 128 * 128;
    d = Wot + (size_t)b * 128 * 128;
    R = 128; C = 128;
    r0 = (rem >> 2) * 32; c0 = (rem & 3) * 32;
  }
  tr32(s, d, R, C, r0, c0, tile);
}

// ---------------- LN, C=512, f32 in (standalone for ln2) -------------------
__global__ __launch_bounds__(256) void ln512_f32(
    const float* __restrict__ x, const float* __restrict__ g,
    const float* __restrict__ b, u16* __restrict__ y)
{
  ln512_body(x, g, b, y, blockIdx.x * 4 + (threadIdx.x >> 6));
}

// ---------------- LN+ReLU, C=2048, bf16 in/out: block-per-row, 1 read ------
__global__ __launch_bounds__(256) void ln2048_bf16_relu(
    const u16* __restrict__ x, const float* __restrict__ g,
    const float* __restrict__ b, u16* __restrict__ y)
{
  const int row = blockIdx.x, tid = threadIdx.x;
  const int c = tid * 8;
  const u16* xr = x + (size_t)row * 2048;
  uint4 u = *(const uint4*)(xr + c);
  u16 e[8]; *(uint4*)e = u;
  float v[8];
#pragma unroll
  for (int i = 0; i < 8; i++) v[i] = b2f(e[i]);
  float s1 = 0.f, s2 = 0.f;
#pragma unroll
  for (int i = 0; i < 8; i++) { s1 += v[i]; s2 += v[i] * v[i]; }
#pragma unroll
  for (int o = 32; o; o >>= 1) { s1 += __shfl_xor(s1, o); s2 += __shfl_xor(s2, o); }
  __shared__ float red[2][4];
  int lane = tid & 63, w = tid >> 6;
  if (lane == 0) { red[0][w] = s1; red[1][w] = s2; }
  __syncthreads();
  s1 = red[0][0] + red[0][1] + red[0][2] + red[0][3];
  s2 = red[1][0] + red[1][1] + red[1][2] + red[1][3];
  float mean = s1 * (1.f / 2048.f);
  float var = s2 * (1.f / 2048.f) - mean * mean;
  float rs = rsqrtf(fmaxf(var, 0.f) + 1e-5f);
  float4 g0 = *(const float4*)(g + c), g1 = *(const float4*)(g + c + 4);
  float4 b0 = *(const float4*)(b + c), b1 = *(const float4*)(b + c + 4);
  float gg[8] = {g0.x, g0.y, g0.z, g0.w, g1.x, g1.y, g1.z, g1.w};
  float bb[8] = {b0.x, b0.y, b0.z, b0.w, b1.x, b1.y, b1.z, b1.w};
  u16 t[8];
#pragma unroll
  for (int i = 0; i < 8; i++)
    t[i] = f2b(fmaxf((v[i] - mean) * rs * gg[i] + bb[i], 0.f));
  *(uint4*)(y + (size_t)row * 2048 + c) = *(const uint4*)t;
}

// ---------------- 128x128-tile MFMA GEMM, 8 waves, K-step 64, gload_lds ----
// (unchanged from R7; see R7 notes for swizzle derivations)
__global__ __launch_bounds__(512, 4) void gemm128(
    const u16* __restrict__ A, int lda,
    const u16* __restrict__ Bt,
    void* __restrict__ C, int ldc, int outf32,
    const float* __restrict__ res,
    int Kslice, int Ktot, int atomic)
{
  __shared__ u16 As[2][128 * 64];
  __shared__ u16 Bs[2][128 * 64];
  const int id = blockIdx.x + gridDim.x * blockIdx.y;
  const int xr = id & 7, xj = id >> 3;
  const int bm = xr * 4 + (xj & 3);
  const int bn = xj >> 2;
  const int m0 = bm * 128, n0 = bn * 128;
  const int kbase = blockIdx.z * Kslice;
  const int tid = threadIdx.x;
  const int lane = tid & 63, w = tid >> 6;
  const int wm = (w & 1) * 64;
  const int wn = (w >> 1) * 32;
  const int l16 = lane & 15, quad = lane >> 4;

  const int sr = tid >> 3;                       // 0..63
  const int sch = (tid & 7) ^ (sr & 7);          // inverse-swizzled source chunk
  const u16* PA = A + (size_t)(m0 + sr) * lda + kbase + sch * 8;
  const u16* PB = Bt + (size_t)(n0 + sr) * Ktot + kbase + sch * 8;
  const size_t askip = (size_t)64 * lda;
  const size_t bskip = (size_t)64 * Ktot;

  f32x4 acc[4][2];
#pragma unroll
  for (int i = 0; i < 4; i++)
#pragma unroll
    for (int j = 0; j < 2; j++) acc[i][j] = (f32x4){0.f, 0.f, 0.f, 0.f};

  {
    gload16(PA, &As[0][w * 512]);
    gload16(PA + askip, &As[0][4096 + w * 512]);
    gload16(PB, &Bs[0][w * 512]);
    gload16(PB + bskip, &Bs[0][4096 + w * 512]);
  }
  __syncthreads();

  int buf = 0;
  for (int kk = 0; kk < Kslice; kk += 64) {
    if (kk + 64 < Kslice) {
      PA += 64; PB += 64;
      gload16(PA, &As[buf ^ 1][w * 512]);
      gload16(PA + askip, &As[buf ^ 1][4096 + w * 512]);
      gload16(PB, &Bs[buf ^ 1][w * 512]);
      gload16(PB + bskip, &Bs[buf ^ 1][4096 + w * 512]);
    }
#pragma unroll
    for (int kc = 0; kc < 2; kc++) {
      bf16x8 af[4], bfr[2];
#pragma unroll
      for (int mt = 0; mt < 4; mt++) {
        int row = wm + mt * 16 + l16;
        af[mt] = *(const bf16x8*)&As[buf][row * 64 + (((kc * 4 + quad) ^ (row & 7)) * 8)];
      }
#pragma unroll
      for (int nt = 0; nt < 2; nt++) {
        int row = wn + nt * 16 + l16;
        bfr[nt] = *(const bf16x8*)&Bs[buf][row * 64 + (((kc * 4 + quad) ^ (row & 7)) * 8)];
      }
#pragma unroll
      for (int mt = 0; mt < 4; mt++)
#pragma unroll
        for (int nt = 0; nt < 2; nt++)
          acc[mt][nt] = __builtin_amdgcn_mfma_f32_16x16x32_bf16(
              af[mt], bfr[nt], acc[mt][nt], 0, 0, 0);
    }
    __syncthreads();
    buf ^= 1;
  }

#pragma unroll
  for (int mt = 0; mt < 4; mt++)
#pragma unroll
    for (int nt = 0; nt < 2; nt++)
#pragma unroll
      for (int r = 0; r < 4; r++) {
        int gr = m0 + wm + mt * 16 + quad * 4 + r;
        int gc = n0 + wn + nt * 16 + l16;
        size_t off = (size_t)gr * ldc + gc;
        float v = acc[mt][nt][r];
        if (atomic) {
          atomicAdd((float*)C + off, v);
        } else {
          if (res) v += res[off];
          if (outf32) ((float*)C)[off] = v;
          else        ((u16*)C)[off] = f2b(v);
        }
      }
}

// ---------------- banded attention TQ=32, 512 thr + fused Wo (+W2 tr) ------
// blockIdx.x < 128: attention, 32 queries x 1 head; band t in [0,128).
// blockIdx.x >= 128: one 32x32 W2-transpose tile (Btqkv dead by now).
// kv: linear [128][128] bf16, chunk-XOR swizzle: element (row r, chunk c)
//   stored at chunk slot c^(r&15) (rule 21: K staged via gload16 with
//   inverse-swizzled per-lane GLOBAL source; V^T scatter writes swizzled;
//   all fragment reads use slot (kc*4+quad)^(row&15) -> <=2-way banks).
// Wo fragments preloaded to registers at kernel start (L2-resident Wot).
#define TQ 32
#define BAND 128
#define QROW 136   // u16 row stride for qp (Q/P/O): 272B => 2-way-max b128
#define PROW 132   // f32 score row stride (132%32=4 -> <=2-way banks)
__global__ __launch_bounds__(512) void attn_mfma(
    const u16* __restrict__ qkv, const float* __restrict__ pos,
    const float* __restrict__ ori, const int* __restrict__ batch,
    const u16* __restrict__ wot, const float* __restrict__ xres,
    float* __restrict__ out,
    const float* __restrict__ W2, u16* __restrict__ W2t)
{
  __shared__ u16 kv[128 * 128];    // K band -> V^T (chunk-swizzled linear)
  __shared__ u16 qp[TQ * QROW];    // Q tile -> P bf16 -> O bf16
  __shared__ float ps[TQ * PROW];  // f32 scores
  __shared__ float bpx[BAND], bpy[BAND], bpz[BAND];
  __shared__ float box_[BAND], boy_[BAND], boz_[BAND];
  __shared__ int bb[BAND];

  if (blockIdx.x >= 128) {         // ---- W2 transpose tile (2048x512) ----
    int idx = (blockIdx.x - 128) + blockIdx.y * 256;   // 0..1023
    int r0 = (idx >> 4) * 32, c0 = (idx & 15) * 32;
    tr32_512(W2, W2t, 2048, 512, r0, c0, (u16(*)[33])kv);
    return;
  }

  const int h = blockIdx.y;
  // XCD-chunked bijective swizzle over the 128 attn x-blocks
  const int bxs = (blockIdx.x & 7) * 16 + (blockIdx.x >> 3);
  const int i0 = bxs * TQ;
  const int j0 = i0 - 48;
  const int tid = threadIdx.x;
  const int lane = tid & 63, w = tid >> 6;          // w in 0..7
  const int l16 = lane & 15, quad = lane >> 4;

  // ---- phase 0: Wo fragments -> registers (hidden under staging) ----
  bf16x8 wof[4];
  {
    const u16* wsrc = wot + (size_t)h * HID * HID + (w * 16 + l16) * HID;
#pragma unroll
    for (int kc = 0; kc < 4; kc++)
      wof[kc] = *(const bf16x8*)&wsrc[kc * 32 + quad * 8];
  }

  // ---- phase 1: stage geometry, K (gload_lds), Q ----
  if (tid < BAND) {
    int t = tid, j = j0 + t;
    if (j >= 0 && j < N_TOK) {
      bpx[t] = pos[j * 3 + 0]; bpy[t] = pos[j * 3 + 1]; bpz[t] = pos[j * 3 + 2];
      box_[t] = ori[j * 3 + 0]; boy_[t] = ori[j * 3 + 1]; boz_[t] = ori[j * 3 + 2];
      bb[t] = batch[j];
    } else {
      bpx[t] = bpy[t] = bpz[t] = 0.f;
      box_[t] = boy_[t] = boz_[t] = 0.f;
      bb[t] = -12345;
    }
  }
  {  // K: 128 rows x 256B via 4 gload16 calls; OOB rows read in-arena garbage
     //    (mask in phase 2 uses only zero-guarded geometry -> never consumed)
    const u16* kbase = qkv + 512 + h * HID;
#pragma unroll
    for (int call = 0; call < 4; call++) {
      int row = call * 32 + w * 4 + (lane >> 4);
      int c = (lane & 15) ^ (row & 15);             // inverse-swizzled source
      const u16* g = kbase + (size_t)(j0 + row) * QKV_LD + c * 8;
      gload16(g, &kv[call * 4096 + w * 512]);
    }
  }
  {  // Q: 32 x 128, one coalesced 16B chunk per thread
    int q = tid >> 4, c8 = (tid & 15) * 8;
    *(int4*)&qp[q * QROW + c8] =
        *(const int4*)&qkv[(size_t)(i0 + q) * QKV_LD + h * HID + c8];
  }
  __syncthreads();

  // ---- phase 2: scores S = Q K^T / sqrt(d) + gbias, masked -> ps ----
  {
    const int t = w * 16 + l16;
    bf16x8 bf[4];                       // K fragments, row tile tt = w
#pragma unroll
    for (int kc = 0; kc < 4; kc++)
      bf[kc] = *(const bf16x8*)&kv[t * 128 + (((kc * 4 + quad) ^ (t & 15)) * 8)];
#pragma unroll
    for (int qt = 0; qt < 2; qt++) {
      bf16x8 af[4];
#pragma unroll
      for (int kc = 0; kc < 4; kc++)
        af[kc] = *(const bf16x8*)&qp[(qt * 16 + l16) * QROW + kc * 32 + quad * 8];
      f32x4 acc = (f32x4){0.f, 0.f, 0.f, 0.f};
#pragma unroll
      for (int kc = 0; kc < 4; kc++)
        acc = __builtin_amdgcn_mfma_f32_16x16x32_bf16(af[kc], bf[kc], acc, 0, 0, 0);
#pragma unroll
      for (int r = 0; r < 4; r++) {
        int q = qt * 16 + quad * 4 + r, iq = q + 48;
        int dseq = iq - t;
        bool ok = (bb[t] == bb[iq]) && (dseq <= 48) && (dseq >= -48);
        {
#pragma clang fp contract(off)
          float dx = bpx[iq] - bpx[t], dy = bpy[iq] - bpy[t], dz = bpz[iq] - bpz[t];
          float d2 = dx * dx + dy * dy + dz * dz;
          ok = ok && (d2 <= 1.0f);
        }
        float s = -1e9f;
        if (ok) {
          float gb = box_[iq] * box_[t] + boy_[iq] * boy_[t] + boz_[iq] * boz_[t];
          s = acc[r] * 0.08838834764831845f + gb;
        }
        ps[q * PROW + t] = s;
      }
    }
  }
  __syncthreads();

  // ---- phase 3: stage V^T (overwrites kv, swizzled) + softmax -> P in qp --
  for (int idx = tid; idx < BAND * 32; idx += 512) {  // V rows -> V^T cols
    int t = idx >> 5, d4 = (idx & 31) * 4;
    int j = j0 + t;
    uint2 val; val.x = 0; val.y = 0;                  // zero-guard: P*garbage
    if (j >= 0 && j < N_TOK)                          // could be NaN otherwise
      val = *(const uint2*)&qkv[(size_t)j * QKV_LD + 1024 + h * HID + d4];
    u16 e[4] = {(u16)val.x, (u16)(val.x >> 16), (u16)val.y, (u16)(val.y >> 16)};
    int ct = t >> 3, cw = t & 7;
#pragma unroll
    for (int jj = 0; jj < 4; jj++) {     // staggered write order
      int dd = (jj + tid) & 3;
      int d = d4 + dd;
      kv[d * 128 + ((ct ^ (d & 15)) * 8) + cw] = e[dd];
    }
  }
  {  // softmax: 32 rows x 16 lanes, 8 elems per lane, shfl_xor reduce
    int row = tid >> 4, sub = tid & 15;
    float vals[8];
    float m = -1e30f;
#pragma unroll
    for (int i = 0; i < 8; i++) {
      vals[i] = ps[row * PROW + sub + i * 16];
      m = fmaxf(m, vals[i]);
    }
#pragma unroll
    for (int o = 8; o; o >>= 1) m = fmaxf(m, __shfl_xor(m, o));
    float s = 0.f;
#pragma unroll
    for (int i = 0; i < 8; i++) { vals[i] = __expf(vals[i] - m); s += vals[i]; }
#pragma unroll
    for (int o = 8; o; o >>= 1) s += __shfl_xor(s, o);
    float inv = 1.f / s;
#pragma unroll
    for (int i = 0; i < 8; i++)
      qp[row * QROW + sub + i * 16] = f2b(vals[i] * inv);
  }
  __syncthreads();

  // ---- phase 5: O = P V via MFMA (A=P[q][t], B=V^T[d][t]) -> O bf16 regs --
  u16 obuf[2][4];
  {
    const int d = w * 16 + l16;
    bf16x8 bf[4];                       // V^T fragments, row tile dt = w
#pragma unroll
    for (int kc = 0; kc < 4; kc++)
      bf[kc] = *(const bf16x8*)&kv[d * 128 + (((kc * 4 + quad) ^ (d & 15)) * 8)];
#pragma unroll
    for (int qt = 0; qt < 2; qt++) {
      bf16x8 paf[4];
#pragma unroll
      for (int kc = 0; kc < 4; kc++)
        paf[kc] = *(const bf16x8*)&qp[(qt * 16 + l16) * QROW + kc * 32 + quad * 8];
      f32x4 acc = (f32x4){0.f, 0.f, 0.f, 0.f};
#pragma unroll
      for (int kc = 0; kc < 4; kc++)
        acc = __builtin_amdgcn_mfma_f32_16x16x32_bf16(paf[kc], bf[kc], acc, 0, 0, 0);
#pragma unroll
      for (int r = 0; r < 4; r++) obuf[qt][r] = f2b(acc[r]);
    }
  }
  __syncthreads();   // all reads of qp (P) complete

  // ---- phase 6: O -> qp [q][d] ----
#pragma unroll
  for (int qt = 0; qt < 2; qt++) {
#pragma unroll
    for (int r = 0; r < 4; r++)
      qp[(qt * 16 + quad * 4 + r) * QROW + w * 16 + l16] = obuf[qt][r];
  }
  __syncthreads();

  // ---- phase 7: out = O @ Wo_h + x (f32), B = preloaded Wo regs ----
  {
#pragma unroll
    for (int qt = 0; qt < 2; qt++) {
      bf16x8 oaf[4];
#pragma unroll
      for (int kc = 0; kc < 4; kc++)
        oaf[kc] = *(const bf16x8*)&qp[(qt * 16 + l16) * QROW + kc * 32 + quad * 8];
      f32x4 acc = (f32x4){0.f, 0.f, 0.f, 0.f};
#pragma unroll
      for (int kc = 0; kc < 4; kc++)
        acc = __builtin_amdgcn_mfma_f32_16x16x32_bf16(oaf[kc], wof[kc], acc, 0, 0, 0);
#pragma unroll
      for (int r = 0; r < 4; r++) {
        int q = qt * 16 + quad * 4 + r;
        size_t off = (size_t)(i0 + q) * C_OUT + h * HID + w * 16 + l16;
        out[off] = acc[r] + xres[off];
      }
    }
  }
}

// ---------------- launcher --------------------------------------------------
// 7 dispatches. ws arena (24 MB), lifetime-aliased:
//   [0,4M)     xn (prep->QKV) -> x1n (ln2->FFN1)
//   [4,16M)    qkv (QKV->attn) -> h [4,20M) (FFN1->FFN2)
//   [16,16.2M) Wot (prep->attn; dead before FFN1 writes h over it)
//   [20,22M)   Btqkv (prep->QKV) -> W2t (attn-launch transpose ->FFN2)
//   [22,24M)   W1t (prep->FFN1)
//   x1 lives in d_out (f32); FFN2 atomically accumulates onto it.
#define MB (1048576)
extern "C" void kernel_launch(void* const* d_in, const int* in_sizes, int n_in,
                              void* d_out, int out_size, void* d_ws, size_t ws_size,
                              hipStream_t stream) {
  const float* x    = (const float*)d_in[0];
  const float* pos  = (const float*)d_in[1];
  const float* ori  = (const float*)d_in[2];
  const int*   batch = (const int*)d_in[4];
  const float* ln1g = (const float*)d_in[5];
  const float* ln1b = (const float*)d_in[6];
  const float* ln2g = (const float*)d_in[7];
  const float* ln2b = (const float*)d_in[8];
  const float* Wq = (const float*)d_in[9];
  const float* Wk = (const float*)d_in[10];
  const float* Wv = (const float*)d_in[11];
  const float* Wo = (const float*)d_in[12];
  const float* lnmg = (const float*)d_in[13];
  const float* lnmb = (const float*)d_in[14];
  const float* W1 = (const float*)d_in[15];
  const float* W2 = (const float*)d_in[16];
  float* out = (float*)d_out;

  char* ws = (char*)d_ws;
  u16* xn    = (u16*)(ws + 0);
  u16* x1n   = (u16*)(ws + 0);
  u16* qkv   = (u16*)(ws + 4 * MB);
  u16* h     = (u16*)(ws + 4 * MB);
  u16* Wot   = (u16*)(ws + 16 * MB);
  u16* Btqkv = (u16*)(ws + 20 * MB);
  u16* W2t   = (u16*)(ws + 20 * MB);
  u16* W1t   = (u16*)(ws + 22 * MB);

  // 1. ln1 + first-phase weight transposes
  prep<<<dim3(2880), 256, 0, stream>>>(x, ln1g, ln1b, xn,
                                       Wq, Wk, Wv, Wo, W1, Btqkv, Wot, W1t);
  // 2. qkv = xn @ [Wq|Wk|Wv]
  gemm128<<<dim3(12, 32, 1), 512, 0, stream>>>(xn, 512, Btqkv, qkv, QKV_LD, 0,
                                               nullptr, 512, 512, 0);
  // 3. attention (TQ=32) + fused Wo + residual -> out (f32); plus W2->W2t
  attn_mfma<<<dim3(384, NH), 512, 0, stream>>>(qkv, pos, ori, batch, Wot, x, out,
                                               W2, W2t);
  // 4. ln2
  ln512_f32<<<dim3(1024), 256, 0, stream>>>(out, ln2g, ln2b, x1n);
  // 5. h = x1n @ W1
  gemm128<<<dim3(16, 32, 1), 512, 0, stream>>>(x1n, 512, W1t, h, 2048, 0,
                                               nullptr, 512, 512, 0);
  // 6. h = relu(LN(h))
  ln2048_bf16_relu<<<dim3(4096), 256, 0, stream>>>(h, lnmg, lnmb, h);
  // 7. out += h @ W2  (split-K x2, atomic f32; out already holds x1)
  gemm128<<<dim3(4, 32, 2), 512, 0, stream>>>(h, 2048, W2t, out, 512, 1,
                                              nullptr, 1024, 2048, 1);
}